// Round 16
// baseline (239.942 us; speedup 1.0000x reference)
//
#include <hip/hip_runtime.h>

// HeteroMessagePassingLayer Round 16:
//  - R14 structure restored (R15 Bresenham interleave reverted: it hurt)
//  - proj GEMM moved INTO the scan_tile launch (independent of scans ->
//    true overlap; scatter gets its own kernel)
//  - nontemporal stores for scatter payloads (write-once read-once data)
//  - GIN gather reads xb_imm (bf16) instead of f32 x_imm

constexpr int D = 256;
constexpr int EPB_LOG = 12;                 // 4096 edges per hist block
constexpr int EPB = 1 << EPB_LOG;
constexpr int MAXW = 10240;                 // LDS hist words (N<=20480)

typedef __attribute__((ext_vector_type(4))) float f32x4v;
typedef __attribute__((ext_vector_type(8))) short short8;

// ---------------------------------------------------------------- utilities
__device__ __forceinline__ float4 ld4(const float* p) {
    return *reinterpret_cast<const float4*>(p);
}
__device__ __forceinline__ void st4(float* p, float4 v) {
    *reinterpret_cast<float4*>(p) = v;
}
__device__ __forceinline__ unsigned short f2bf(float f) {
    unsigned u = __float_as_uint(f);
    u = u + 0x7FFFu + ((u >> 16) & 1u);
    return (unsigned short)(u >> 16);
}
__device__ __forceinline__ float bf2f(unsigned short u) {
    return __uint_as_float(((unsigned)u) << 16);
}
__device__ __forceinline__ float4 ldb4(const unsigned short* p) {
    ushort4 u = *reinterpret_cast<const ushort4*>(p);
    return make_float4(bf2f(u.x), bf2f(u.y), bf2f(u.z), bf2f(u.w));
}
__device__ __forceinline__ float wave_sum(float p) {
#pragma unroll
    for (int off = 32; off > 0; off >>= 1) p += __shfl_xor(p, off, 64);
    return p;
}
__device__ __forceinline__ float gat_partial(float4 h, float4 hrv, float ea,
                                             float4 We4, float4 att4) {
    float z, pp = 0.f;
    z = h.x + hrv.x + ea * We4.x; z *= (z > 0.f) ? 1.0f : 0.2f; pp += z * att4.x;
    z = h.y + hrv.y + ea * We4.y; z *= (z > 0.f) ? 1.0f : 0.2f; pp += z * att4.y;
    z = h.z + hrv.z + ea * We4.z; z *= (z > 0.f) ? 1.0f : 0.2f; pp += z * att4.z;
    z = h.w + hrv.w + ea * We4.w; z *= (z > 0.f) ? 1.0f : 0.2f; pp += z * att4.w;
    return pp;
}

// ============ k_front: LDS hist blocks FIRST, then casts, then W transposes
__global__ __launch_bounds__(256)
void k_front(const float* __restrict__ x_glom, const float* __restrict__ x_imm,
             unsigned short* __restrict__ xb_glom, unsigned short* __restrict__ xb_imm,
             const float* __restrict__ W0, const float* __restrict__ W1,
             const float* __restrict__ W2, const float* __restrict__ W3,
             unsigned short* __restrict__ Wt,
             const int* __restrict__ ei_gg, const int* __restrict__ ei_ig,
             const int* __restrict__ ei_gi,
             unsigned* __restrict__ blockhist, unsigned short* __restrict__ rank16,
             int n4, int nbCast, int nbH, int E, int N)
{
    __shared__ unsigned ldsh[MAXW];
    int bx = blockIdx.x;
    if (bx < 3 * nbH) {
        // ---- LDS histogram: counts + local rank ----
        int t = bx / nbH;
        int b = bx - t * nbH;
        const int* ei = (t == 0) ? ei_gg : (t == 1) ? ei_ig : ei_gi;
        const int Nw = (N + 1) >> 1;
        for (int w = threadIdx.x; w < Nw; w += 256) ldsh[w] = 0u;
        __syncthreads();
        int e0 = b << EPB_LOG;
#pragma unroll
        for (int it = 0; it < EPB / 256; ++it) {
            int e = e0 + it * 256 + threadIdx.x;
            if (e < E) {
                int d = ei[E + e];
                unsigned sh = (d & 1) * 16;
                unsigned old = atomicAdd(&ldsh[d >> 1], 1u << sh);
                rank16[(size_t)t * E + e] = (unsigned short)((old >> sh) & 0xFFFFu);
            }
        }
        __syncthreads();
        unsigned* dst = blockhist + (size_t)(t * nbH + b) * Nw;
        for (int w = threadIdx.x; w < Nw; w += 256) dst[w] = ldsh[w];
        return;
    }
    bx -= 3 * nbH;
    if (bx < 2 * nbCast) {
        // ---- casts ----
        bool second = (bx >= nbCast);
        int i = (second ? bx - nbCast : bx) * 256 + threadIdx.x;
        if (i < n4) {
            const float* x = second ? x_imm : x_glom;
            unsigned short* y = second ? xb_imm : xb_glom;
            float4 v = ld4(x + (size_t)i * 4);
            ushort4 o;
            o.x = f2bf(v.x); o.y = f2bf(v.y); o.z = f2bf(v.z); o.w = f2bf(v.w);
            *reinterpret_cast<ushort4*>(y + (size_t)i * 4) = o;
        }
        return;
    }
    bx -= 2 * nbCast;
    {
        // ---- W transposes (bf16, order Wgcn, Wr, Wl, Wgin) ----
        int w = bx >> 8;
        int i = ((bx & 255) << 8) + threadIdx.x;
        const float* W = (w == 0) ? W0 : (w == 1) ? W1 : (w == 2) ? W2 : W3;
        int c = i >> 8, k = i & 255;
        Wt[(size_t)w * D * D + i] = f2bf(W[k * D + c]);
    }
}

// --------------------------------------------------------------- scans
__device__ __forceinline__ unsigned hist_get(const unsigned* __restrict__ bh,
                                             int Nw, int nbH, int t, int b, int d)
{
    unsigned w = bh[(size_t)(t * nbH + b) * Nw + (d >> 1)];
    return (w >> ((d & 1) * 16)) & 0xFFFFu;
}

// ====== k_scanproj: scan-tile blocks (3*TPT) first, then proj GEMM blocks.
// proj depends only on k_front outputs -> overlaps the scan work.
__global__ __launch_bounds__(256)
void k_scanproj(const unsigned* __restrict__ blockhist, int* __restrict__ rows,
                int* __restrict__ partials, int N, int TPT, int nbH,
                const unsigned short* __restrict__ xbg,
                const unsigned short* __restrict__ xbi,
                const unsigned short* __restrict__ Wt,
                const float* __restrict__ br, const float* __restrict__ bl,
                unsigned short* __restrict__ xw, unsigned short* __restrict__ hr,
                unsigned short* __restrict__ hl, int M)
{
    int bx = blockIdx.x;
    if (bx < 3 * TPT) {
        // ------------------------------ scan tile --------------------------
        int t = bx / TPT, tile = bx - t * TPT;
        int i = tile * 256 + threadIdx.x;
        const int Nw = (N + 1) >> 1;
        __shared__ int sh[256];
        int v = 0;
        if (i < N)
            for (int b = 0; b < nbH; ++b)
                v += (int)hist_get(blockhist, Nw, nbH, t, b, i);
        sh[threadIdx.x] = v;
        __syncthreads();
#pragma unroll
        for (int off = 1; off < 256; off <<= 1) {
            int add = (threadIdx.x >= off) ? sh[threadIdx.x - off] : 0;
            __syncthreads();
            sh[threadIdx.x] += add;
            __syncthreads();
        }
        if (i < N) rows[(size_t)t * (N + 1) + i] = sh[threadIdx.x] - v;
        if (threadIdx.x == 255) partials[t * TPT + tile] = sh[255];
        return;
    }
    // ------------------------------- proj GEMM -----------------------------
    int pp = bx - 3 * TPT;
    int brow = pp / 12;
    int yy   = pp - brow * 12;
    const int lane = threadIdx.x & 63;
    const int wave = threadIdx.x >> 6;
    const int lr = lane & 15;
    const int lk = lane >> 4;
    const int row0 = brow * 256 + wave * 64;

    const unsigned short* A;
    const unsigned short* Bt0;
    int col0;
    if (yy < 8) { A = xbg; Bt0 = Wt;             col0 = yy * 64; }
    else        { A = xbi; Bt0 = Wt + 2 * D * D; col0 = (yy - 8) * 64; }

    const unsigned short* ap[4];
#pragma unroll
    for (int rf = 0; rf < 4; ++rf) {
        int arow = row0 + rf * 16 + lr;
        int arow_c = (arow < M) ? arow : (M - 1);
        ap[rf] = A + (size_t)arow_c * D + lk * 8;
    }
    const unsigned short* bp = Bt0 + (size_t)(col0 + lr) * D + lk * 8;

    f32x4v acc[4][4] = {};
#pragma unroll
    for (int k0 = 0; k0 < 256; k0 += 32) {
        short8 af[4], bf[4];
#pragma unroll
        for (int rf = 0; rf < 4; ++rf)
            af[rf] = *reinterpret_cast<const short8*>(ap[rf] + k0);
#pragma unroll
        for (int nf = 0; nf < 4; ++nf)
            bf[nf] = *reinterpret_cast<const short8*>(bp + (size_t)nf * 16 * D + k0);
#pragma unroll
        for (int rf = 0; rf < 4; ++rf)
#pragma unroll
            for (int nf = 0; nf < 4; ++nf)
                acc[rf][nf] = __builtin_amdgcn_mfma_f32_16x16x32_bf16(
                    af[rf], bf[nf], acc[rf][nf], 0, 0, 0);
    }

#pragma unroll
    for (int nf = 0; nf < 4; ++nf) {
        int c = col0 + nf * 16 + lr;
        unsigned short* dst;
        int cc;
        float bv;
        if (yy < 8) {
            if (c < 256) { dst = xw; cc = c;       bv = 0.f;    }
            else         { dst = hr; cc = c - 256; bv = br[cc]; }
        } else           { dst = hl; cc = c;       bv = bl[cc]; }
#pragma unroll
        for (int rf = 0; rf < 4; ++rf) {
#pragma unroll
            for (int i = 0; i < 4; ++i) {
                int r = row0 + rf * 16 + 4 * lk + i;
                if (r < M)
                    dst[(size_t)r * D + cc] = f2bf(acc[rf][nf][i] + bv);
            }
        }
    }
}

__global__ __launch_bounds__(128)
void k_scan_part(int* __restrict__ partials, int TPT)
{
    int t = blockIdx.x;
    __shared__ int sh[128];
    int v = (threadIdx.x < TPT) ? partials[t * TPT + threadIdx.x] : 0;
    sh[threadIdx.x] = v;
    __syncthreads();
#pragma unroll
    for (int off = 1; off < 128; off <<= 1) {
        int add = (threadIdx.x >= off) ? sh[threadIdx.x - off] : 0;
        __syncthreads();
        sh[threadIdx.x] += add;
        __syncthreads();
    }
    if (threadIdx.x < TPT) partials[t * TPT + threadIdx.x] = sh[threadIdx.x] - v;
}

// finalize rows; emit per-(block,bin) ABSOLUTE i32 bases rel32 = rows+prefix
__global__ void k_scan_final(int* __restrict__ rows, const int* __restrict__ partials,
                             const unsigned* __restrict__ blockhist,
                             int* __restrict__ rel32,
                             int N, int TPT, int nbH, int E)
{
    int i = blockIdx.x * 256 + threadIdx.x;
    if (i >= 3 * N) return;
    int t = i / N, j = i - t * N;
    const int Nw = (N + 1) >> 1;
    int run = rows[(size_t)t * (N + 1) + j] + partials[t * TPT + (j >> 8)];
    rows[(size_t)t * (N + 1) + j] = run;
    if (j == 0) rows[(size_t)t * (N + 1) + N] = E;
    int acc = run;
    for (int b = 0; b < nbH; ++b) {
        rel32[(size_t)(t * nbH + b) * N + j] = acc;
        acc += (int)hist_get(blockhist, Nw, nbH, t, b, j);
    }
}

// ======================= scatter: 1 random read/edge, nontemporal stores
__global__ __launch_bounds__(256)
void k_scatter(const int* __restrict__ ei_gg, const int* __restrict__ ei_ig,
               const int* __restrict__ ei_gi, const float* __restrict__ ew_gg,
               const float* __restrict__ ea_ig,
               const int* __restrict__ rel32, const unsigned short* __restrict__ rank16,
               long long* __restrict__ pk_gcn, long long* __restrict__ pk_gat,
               int* __restrict__ src_gin, int nbE, int nbH, int E, int N)
{
    int bx = blockIdx.x;
    int t = bx / nbE;
    int blk = bx - t * nbE;
    int e = blk * 256 + threadIdx.x;
    if (e >= E) return;
    int b = e >> EPB_LOG;
    const int* rel = rel32 + (size_t)(t * nbH + b) * N;
    if (t == 0) {
        int s = ei_gg[e], d = ei_gg[E + e];
        int pos = rel[d] + (int)rank16[e];
        long long v = ((long long)(unsigned)__float_as_uint(ew_gg[e]) << 32)
                    | (unsigned)s;
        __builtin_nontemporal_store(v, &pk_gcn[pos]);
    } else if (t == 1) {
        int s = ei_ig[e], d = ei_ig[E + e];
        int pos = rel[d] + (int)rank16[(size_t)E + e];
        long long v = ((long long)(unsigned)__float_as_uint(ea_ig[e]) << 32)
                    | (unsigned)s;
        __builtin_nontemporal_store(v, &pk_gat[pos]);
    } else {
        int s = ei_gi[e], d = ei_gi[E + e];
        int pos = rel[d] + (int)rank16[2 * (size_t)E + e];
        __builtin_nontemporal_store(s, &src_gin[pos]);
    }
}

// ---------- dinv from CSR values: dinv[d] = rsqrt(1 + sum of incoming ew)
__global__ void k_deg(const int* __restrict__ rows, const int2* __restrict__ pk,
                      float* __restrict__ dinv, int N)
{
    int d = blockIdx.x * 256 + threadIdx.x;
    if (d >= N) return;
    float s = 1.0f;
    int p1 = rows[d + 1];
    for (int p = rows[d]; p < p1; ++p) s += __int_as_float(pk[p].y);
    dinv[d] = rsqrtf(s);
}

// ------------------------------------- GIN GEMM + fused LayerNorm + ReLU
__global__ __launch_bounds__(256)
void k_gin_gemm_ln(const unsigned short* __restrict__ A,
                   const unsigned short* __restrict__ Bt,
                   const float* __restrict__ bias,
                   const float* __restrict__ gamma, const float* __restrict__ beta,
                   float* __restrict__ out, int M)
{
    __shared__ float lds_s[4][64];
    __shared__ float lds_q[4][64];
    const int lane = threadIdx.x & 63;
    const int wave = threadIdx.x >> 6;
    const int lr = lane & 15;
    const int lk = lane >> 4;
    const int row0 = blockIdx.x * 64;
    const int col0 = wave * 64;

    const unsigned short* ap[4];
#pragma unroll
    for (int rf = 0; rf < 4; ++rf) {
        int arow = row0 + rf * 16 + lr;
        int arow_c = (arow < M) ? arow : (M - 1);
        ap[rf] = A + (size_t)arow_c * D + lk * 8;
    }
    const unsigned short* bp = Bt + (size_t)(col0 + lr) * D + lk * 8;

    f32x4v acc[4][4] = {};
#pragma unroll
    for (int k0 = 0; k0 < 256; k0 += 32) {
        short8 af[4], bf[4];
#pragma unroll
        for (int rf = 0; rf < 4; ++rf)
            af[rf] = *reinterpret_cast<const short8*>(ap[rf] + k0);
#pragma unroll
        for (int nf = 0; nf < 4; ++nf)
            bf[nf] = *reinterpret_cast<const short8*>(bp + (size_t)nf * 16 * D + k0);
#pragma unroll
        for (int rf = 0; rf < 4; ++rf)
#pragma unroll
            for (int nf = 0; nf < 4; ++nf)
                acc[rf][nf] = __builtin_amdgcn_mfma_f32_16x16x32_bf16(
                    af[rf], bf[nf], acc[rf][nf], 0, 0, 0);
    }

    float bv[4], gv[4], be[4];
#pragma unroll
    for (int nf = 0; nf < 4; ++nf) {
        int c = col0 + nf * 16 + lr;
        bv[nf] = bias[c]; gv[nf] = gamma[c]; be[nf] = beta[c];
    }

#pragma unroll
    for (int rf = 0; rf < 4; ++rf) {
        float ps[4], pq[4];
#pragma unroll
        for (int i = 0; i < 4; ++i) {
            float s = 0.f, q = 0.f;
#pragma unroll
            for (int nf = 0; nf < 4; ++nf) {
                float v = acc[rf][nf][i] + bv[nf];
                acc[rf][nf][i] = v;
                s += v; q += v * v;
            }
            ps[i] = s; pq[i] = q;
        }
#pragma unroll
        for (int off = 1; off < 16; off <<= 1) {
#pragma unroll
            for (int i = 0; i < 4; ++i) {
                ps[i] += __shfl_xor(ps[i], off, 64);
                pq[i] += __shfl_xor(pq[i], off, 64);
            }
        }
        if (lr == 0) {
#pragma unroll
            for (int i = 0; i < 4; ++i) {
                lds_s[wave][rf * 16 + lk * 4 + i] = ps[i];
                lds_q[wave][rf * 16 + lk * 4 + i] = pq[i];
            }
        }
    }
    __syncthreads();

#pragma unroll
    for (int rf = 0; rf < 4; ++rf) {
#pragma unroll
        for (int i = 0; i < 4; ++i) {
            int rl = rf * 16 + 4 * lk + i;
            float s = lds_s[0][rl] + lds_s[1][rl] + lds_s[2][rl] + lds_s[3][rl];
            float q = lds_q[0][rl] + lds_q[1][rl] + lds_q[2][rl] + lds_q[3][rl];
            float mu  = s * (1.0f / 256.0f);
            float var = q * (1.0f / 256.0f) - mu * mu;
            float rs  = rsqrtf(var + 1e-5f);
            int r = row0 + rl;
            if (r < M) {
#pragma unroll
                for (int nf = 0; nf < 4; ++nf) {
                    out[(size_t)r * D + col0 + nf * 16 + lr] =
                        fmaxf(0.f, (acc[rf][nf][i] - mu) * rs * gv[nf] + be[nf]);
                }
            }
        }
    }
}

// ================== fused gather (full-wave): glom GCN+GATv2+LN, GIN agg
__global__ __launch_bounds__(256)
void k_gather_fused(const unsigned short* __restrict__ xw,
                    const unsigned short* __restrict__ hl,
                    const unsigned short* __restrict__ hr,
                    const float* __restrict__ dinv,
                    const int* __restrict__ rows_gcn, const int2* __restrict__ pk_gcn,
                    const int* __restrict__ rows_gat, const int2* __restrict__ pk_gat,
                    const float* __restrict__ We, const float* __restrict__ att,
                    const float* __restrict__ b_gcn, const float* __restrict__ b_gat,
                    const float* __restrict__ gamma, const float* __restrict__ beta,
                    float* __restrict__ glom_out,
                    const unsigned short* __restrict__ xb_glom,
                    const unsigned short* __restrict__ xb_imm,
                    const float* __restrict__ eps,
                    const int* __restrict__ rows_gin, const int* __restrict__ src_gin,
                    unsigned short* __restrict__ agg,
                    int N)
{
    int gw   = __builtin_amdgcn_readfirstlane((blockIdx.x * 256 + threadIdx.x) >> 6);
    int lane = threadIdx.x & 63;

    if (gw < N) {
        // ------------------------------ glom path -------------------------
        int node = gw;
        float4 We4  = ld4(&We[lane * 4]);
        float4 att4 = ld4(&att[lane * 4]);
        float4 hrv  = ldb4(&hr[(size_t)node * D + lane * 4]);

        float di = dinv[node];
        float4 acc = ldb4(&xw[(size_t)node * D + lane * 4]);
        float4 g0  = ld4(&b_gcn[lane * 4]);
        float4 a0  = ld4(&b_gat[lane * 4]);
        float sc0 = di * di;
        acc.x = sc0 * acc.x + g0.x + a0.x;
        acc.y = sc0 * acc.y + g0.y + a0.y;
        acc.z = sc0 * acc.z + g0.z + a0.z;
        acc.w = sc0 * acc.w + g0.w + a0.w;

        // ---- GCN neighbor sum, 4 edges in flight; coef = w*dinv[s]*di ----
        int p  = rows_gcn[node];
        int p1 = rows_gcn[node + 1];
        for (; p + 4 <= p1; p += 4) {
            int2  pk[4];
            float cf[4];
            float4 v[4];
#pragma unroll
            for (int j = 0; j < 4; ++j) pk[j] = pk_gcn[p + j];
#pragma unroll
            for (int j = 0; j < 4; ++j)
                cf[j] = __int_as_float(pk[j].y) * dinv[pk[j].x] * di;
#pragma unroll
            for (int j = 0; j < 4; ++j) v[j] = ldb4(&xw[(size_t)pk[j].x * D + lane * 4]);
#pragma unroll
            for (int j = 0; j < 4; ++j) {
                acc.x += cf[j] * v[j].x; acc.y += cf[j] * v[j].y;
                acc.z += cf[j] * v[j].z; acc.w += cf[j] * v[j].w;
            }
        }
        for (; p < p1; ++p) {
            int2 pk = pk_gcn[p];
            float cx = __int_as_float(pk.y) * dinv[pk.x] * di;
            float4 v = ldb4(&xw[(size_t)pk.x * D + lane * 4]);
            acc.x += cx * v.x; acc.y += cx * v.y;
            acc.z += cx * v.z; acc.w += cx * v.w;
        }

        // ---- GATv2: unnormalized exp (logits bounded), 4 edges in flight --
        int q  = rows_gat[node];
        int q1 = rows_gat[node + 1];
        int has = (q1 > q);
        float den = 0.f;
        float4 ag = make_float4(0.f, 0.f, 0.f, 0.f);
        for (; q + 4 <= q1; q += 4) {
            int2  pk[4];
            float4 h[4];
            float pp[4];
#pragma unroll
            for (int j = 0; j < 4; ++j) pk[j] = pk_gat[q + j];
#pragma unroll
            for (int j = 0; j < 4; ++j) h[j] = ldb4(&hl[(size_t)pk[j].x * D + lane * 4]);
#pragma unroll
            for (int j = 0; j < 4; ++j)
                pp[j] = wave_sum(gat_partial(h[j], hrv, __int_as_float(pk[j].y), We4, att4));
            float x[4];
#pragma unroll
            for (int j = 0; j < 4; ++j) x[j] = __expf(pp[j]);
            den += (x[0] + x[1]) + (x[2] + x[3]);
#pragma unroll
            for (int j = 0; j < 4; ++j) {
                ag.x += x[j] * h[j].x; ag.y += x[j] * h[j].y;
                ag.z += x[j] * h[j].z; ag.w += x[j] * h[j].w;
            }
        }
        for (; q < q1; ++q) {
            int2 pk = pk_gat[q];
            float4 h = ldb4(&hl[(size_t)pk.x * D + lane * 4]);
            float pp = wave_sum(gat_partial(h, hrv, __int_as_float(pk.y), We4, att4));
            float x = __expf(pp);
            den += x;
            ag.x += x * h.x; ag.y += x * h.y;
            ag.z += x * h.z; ag.w += x * h.w;
        }
        if (has) {
            float inv = 1.0f / den;
            acc.x += ag.x * inv; acc.y += ag.y * inv;
            acc.z += ag.z * inv; acc.w += ag.w * inv;
        }

        // ---- LayerNorm + ReLU ----
        float s_ = acc.x + acc.y + acc.z + acc.w;
        float sq = acc.x * acc.x + acc.y * acc.y + acc.z * acc.z + acc.w * acc.w;
#pragma unroll
        for (int off = 32; off > 0; off >>= 1) {
            s_ += __shfl_xor(s_, off, 64);
            sq += __shfl_xor(sq, off, 64);
        }
        float mu  = s_ * (1.0f / 256.0f);
        float var = sq * (1.0f / 256.0f) - mu * mu;
        float rs  = rsqrtf(var + 1e-5f);
        float4 g = ld4(&gamma[lane * 4]);
        float4 b = ld4(&beta[lane * 4]);
        float4 o;
        o.x = fmaxf(0.f, (acc.x - mu) * rs * g.x + b.x);
        o.y = fmaxf(0.f, (acc.y - mu) * rs * g.y + b.y);
        o.z = fmaxf(0.f, (acc.z - mu) * rs * g.z + b.z);
        o.w = fmaxf(0.f, (acc.w - mu) * rs * g.w + b.w);
        st4(&glom_out[(size_t)node * D + lane * 4], o);
    } else if (gw < 2 * N) {
        // ------------------------------ gin path --------------------------
        int node = gw - N;
        float c = 1.0f + eps[0];
        float4 acc = ldb4(&xb_imm[(size_t)node * D + lane * 4]);
        acc.x *= c; acc.y *= c; acc.z *= c; acc.w *= c;
        int p  = rows_gin[node];
        int p1 = rows_gin[node + 1];
        for (; p + 4 <= p1; p += 4) {
            int s[4];
            float4 v[4];
#pragma unroll
            for (int j = 0; j < 4; ++j) s[j] = src_gin[p + j];
#pragma unroll
            for (int j = 0; j < 4; ++j) v[j] = ldb4(&xb_glom[(size_t)s[j] * D + lane * 4]);
            acc.x += (v[0].x + v[1].x) + (v[2].x + v[3].x);
            acc.y += (v[0].y + v[1].y) + (v[2].y + v[3].y);
            acc.z += (v[0].z + v[1].z) + (v[2].z + v[3].z);
            acc.w += (v[0].w + v[1].w) + (v[2].w + v[3].w);
        }
        for (; p < p1; ++p) {
            int sx = src_gin[p];
            float4 v = ldb4(&xb_glom[(size_t)sx * D + lane * 4]);
            acc.x += v.x; acc.y += v.y; acc.z += v.z; acc.w += v.w;
        }
        ushort4 o;
        o.x = f2bf(acc.x); o.y = f2bf(acc.y); o.z = f2bf(acc.z); o.w = f2bf(acc.w);
        *reinterpret_cast<ushort4*>(agg + (size_t)node * D + lane * 4) = o;
    }
}

// ------------------------------------------------------------------ launch
extern "C" void kernel_launch(void* const* d_in, const int* in_sizes, int n_in,
                              void* d_out, int out_size, void* d_ws, size_t ws_size,
                              hipStream_t stream)
{
    const float* x_glom = (const float*)d_in[0];
    const float* x_imm  = (const float*)d_in[1];
    const float* ew_gg  = (const float*)d_in[2];
    const float* ea_ig  = (const float*)d_in[3];
    const float* W_gcn  = (const float*)d_in[4];
    const float* b_gcn  = (const float*)d_in[5];
    const float* Wl     = (const float*)d_in[6];
    const float* bl     = (const float*)d_in[7];
    const float* Wr     = (const float*)d_in[8];
    const float* br     = (const float*)d_in[9];
    const float* att    = (const float*)d_in[10];
    const float* We     = (const float*)d_in[11];
    const float* b_gat  = (const float*)d_in[12];
    const float* eps    = (const float*)d_in[13];
    const float* W_gin  = (const float*)d_in[14];
    const float* b_gin  = (const float*)d_in[15];
    const float* gamma  = (const float*)d_in[16];
    const float* beta   = (const float*)d_in[17];
    const int*   ei_gg  = (const int*)d_in[18];
    const int*   ei_ig  = (const int*)d_in[19];
    const int*   ei_gi  = (const int*)d_in[20];

    const int N = in_sizes[0] / D;     // 20000
    const int E = in_sizes[2];         // 320000
    const size_t ND = (size_t)N * D;
    const int TPT = (N + 255) / 256;
    const int nbH = (E + EPB - 1) / EPB;       // hist blocks per type (79)

    // ---- workspace layout ----
    char* base = (char*)d_ws;
    size_t off = 0;
    auto alloc = [&](size_t bytes) {
        void* p = base + off;
        off = (off + bytes + 255) & ~(size_t)255;
        return p;
    };
    unsigned short* xb_glom = (unsigned short*)alloc(ND * 2);
    unsigned short* xb_imm  = (unsigned short*)alloc(ND * 2);
    unsigned short* xw_b    = (unsigned short*)alloc(ND * 2);
    unsigned short* hl_b    = (unsigned short*)alloc(ND * 2);
    unsigned short* hr_b    = (unsigned short*)alloc(ND * 2);
    unsigned short* agg_b   = (unsigned short*)alloc(ND * 2);   // aliases blockhist
    unsigned*       blockhist = (unsigned*)agg_b;               // dead before gather
    unsigned short* Wt      = (unsigned short*)alloc(4 * D * D * 2);
    float* dinv    = (float*)alloc((size_t)N * 4);
    int*   rows    = (int*)alloc(3 * (size_t)(N + 1) * 4);
    int*   parts   = (int*)alloc(3 * (size_t)TPT * 4);
    int*   rel32   = (int*)alloc(3 * (size_t)nbH * N * 4);
    unsigned short* rank16 = (unsigned short*)alloc(3 * (size_t)E * 2);
    int2*  pk_gcn  = (int2*)alloc((size_t)E * 8);
    int2*  pk_gat  = (int2*)alloc((size_t)E * 8);
    int*   src_gin = (int*)alloc((size_t)E * 4);

    float* glom_out = (float*)d_out;
    float* imm_out  = (float*)d_out + ND;

    const int n4      = (int)(ND / 4);
    const int nbCast  = (n4 + 255) / 256;          // 5000
    const int nbE     = (E + 255) / 256;           // 1250 scatter blocks/type
    const int nb_3n   = (3 * N + 255) / 256;
    const int nb_2nw  = (2 * N + 3) / 4;
    const int nbProj  = ((N + 255) / 256) * 12;    // 948

    // 1. front: LDS hist (no global atomics) || casts || W transposes
    k_front<<<3 * nbH + 2 * nbCast + 1024, 256, 0, stream>>>(
        x_glom, x_imm, xb_glom, xb_imm,
        W_gcn, Wr, Wl, W_gin, Wt,
        ei_gg, ei_ig, ei_gi,
        blockhist, rank16, n4, nbCast, nbH, E, N);
    // 2. scan-tile || proj GEMM (independent; true overlap)
    k_scanproj<<<3 * TPT + nbProj, 256, 0, stream>>>(
        blockhist, rows, parts, N, TPT, nbH,
        xb_glom, xb_imm, Wt, br, bl, xw_b, hr_b, hl_b, N);
    // 3-4. scan chain
    k_scan_part<<<3, 128, 0, stream>>>(parts, TPT);
    k_scan_final<<<nb_3n, 256, 0, stream>>>(rows, parts, blockhist, rel32,
                                            N, TPT, nbH, E);
    // 5. scatter (nontemporal stores)
    k_scatter<<<3 * nbE, 256, 0, stream>>>(
        ei_gg, ei_ig, ei_gi, ew_gg, ea_ig,
        rel32, rank16, (long long*)pk_gcn, (long long*)pk_gat, src_gin,
        nbE, nbH, E, N);
    // 6. dinv from CSR values
    k_deg<<<(N + 255) / 256, 256, 0, stream>>>(rows, pk_gcn, dinv, N);
    // 7. fused gathers (full-wave)
    k_gather_fused<<<nb_2nw, 256, 0, stream>>>(
        xw_b, hl_b, hr_b, dinv,
        rows, pk_gcn,
        rows + (N + 1), pk_gat,
        We, att, b_gcn, b_gat, gamma, beta, glom_out,
        xb_glom, xb_imm, eps,
        rows + 2 * (N + 1), src_gin, agg_b, N);
    // 8. GIN GEMM + fused LN + ReLU
    k_gin_gemm_ln<<<(N + 63) / 64, 256, 0, stream>>>(
        agg_b, Wt + 3 * D * D, b_gin, gamma, beta, imm_out, N);
}

// Round 17
// 230.491 us; speedup vs baseline: 1.0410x; 1.0410x over previous
//
#include <hip/hip_runtime.h>

// HeteroMessagePassingLayer Round 17:
//  - R14 (best-known, 226.6us) restored verbatim: k_mid = proj GEMM blocks +
//    scatter blocks, regular stores (R16's nontemporal stores reverted)
//  - k_scan_part folded into k_scan_final (per-thread partial prefix over
//    <=79 tile sums) -> one fewer launch
//  - GIN gather reads xb_imm (bf16) instead of f32 x_imm

constexpr int D = 256;
constexpr int EPB_LOG = 12;                 // 4096 edges per hist block
constexpr int EPB = 1 << EPB_LOG;
constexpr int MAXW = 10240;                 // LDS hist words (N<=20480)

typedef __attribute__((ext_vector_type(4))) float f32x4v;
typedef __attribute__((ext_vector_type(8))) short short8;

// ---------------------------------------------------------------- utilities
__device__ __forceinline__ float4 ld4(const float* p) {
    return *reinterpret_cast<const float4*>(p);
}
__device__ __forceinline__ void st4(float* p, float4 v) {
    *reinterpret_cast<float4*>(p) = v;
}
__device__ __forceinline__ unsigned short f2bf(float f) {
    unsigned u = __float_as_uint(f);
    u = u + 0x7FFFu + ((u >> 16) & 1u);
    return (unsigned short)(u >> 16);
}
__device__ __forceinline__ float bf2f(unsigned short u) {
    return __uint_as_float(((unsigned)u) << 16);
}
__device__ __forceinline__ float4 ldb4(const unsigned short* p) {
    ushort4 u = *reinterpret_cast<const ushort4*>(p);
    return make_float4(bf2f(u.x), bf2f(u.y), bf2f(u.z), bf2f(u.w));
}
__device__ __forceinline__ float wave_sum(float p) {
#pragma unroll
    for (int off = 32; off > 0; off >>= 1) p += __shfl_xor(p, off, 64);
    return p;
}
__device__ __forceinline__ float gat_partial(float4 h, float4 hrv, float ea,
                                             float4 We4, float4 att4) {
    float z, pp = 0.f;
    z = h.x + hrv.x + ea * We4.x; z *= (z > 0.f) ? 1.0f : 0.2f; pp += z * att4.x;
    z = h.y + hrv.y + ea * We4.y; z *= (z > 0.f) ? 1.0f : 0.2f; pp += z * att4.y;
    z = h.z + hrv.z + ea * We4.z; z *= (z > 0.f) ? 1.0f : 0.2f; pp += z * att4.z;
    z = h.w + hrv.w + ea * We4.w; z *= (z > 0.f) ? 1.0f : 0.2f; pp += z * att4.w;
    return pp;
}

// ============ k_front: LDS hist blocks FIRST, then casts, then W transposes
__global__ __launch_bounds__(256)
void k_front(const float* __restrict__ x_glom, const float* __restrict__ x_imm,
             unsigned short* __restrict__ xb_glom, unsigned short* __restrict__ xb_imm,
             const float* __restrict__ W0, const float* __restrict__ W1,
             const float* __restrict__ W2, const float* __restrict__ W3,
             unsigned short* __restrict__ Wt,
             const int* __restrict__ ei_gg, const int* __restrict__ ei_ig,
             const int* __restrict__ ei_gi,
             unsigned* __restrict__ blockhist, unsigned short* __restrict__ rank16,
             int n4, int nbCast, int nbH, int E, int N)
{
    __shared__ unsigned ldsh[MAXW];
    int bx = blockIdx.x;
    if (bx < 3 * nbH) {
        // ---- LDS histogram: counts + local rank ----
        int t = bx / nbH;
        int b = bx - t * nbH;
        const int* ei = (t == 0) ? ei_gg : (t == 1) ? ei_ig : ei_gi;
        const int Nw = (N + 1) >> 1;
        for (int w = threadIdx.x; w < Nw; w += 256) ldsh[w] = 0u;
        __syncthreads();
        int e0 = b << EPB_LOG;
#pragma unroll
        for (int it = 0; it < EPB / 256; ++it) {
            int e = e0 + it * 256 + threadIdx.x;
            if (e < E) {
                int d = ei[E + e];
                unsigned sh = (d & 1) * 16;
                unsigned old = atomicAdd(&ldsh[d >> 1], 1u << sh);
                rank16[(size_t)t * E + e] = (unsigned short)((old >> sh) & 0xFFFFu);
            }
        }
        __syncthreads();
        unsigned* dst = blockhist + (size_t)(t * nbH + b) * Nw;
        for (int w = threadIdx.x; w < Nw; w += 256) dst[w] = ldsh[w];
        return;
    }
    bx -= 3 * nbH;
    if (bx < 2 * nbCast) {
        // ---- casts ----
        bool second = (bx >= nbCast);
        int i = (second ? bx - nbCast : bx) * 256 + threadIdx.x;
        if (i < n4) {
            const float* x = second ? x_imm : x_glom;
            unsigned short* y = second ? xb_imm : xb_glom;
            float4 v = ld4(x + (size_t)i * 4);
            ushort4 o;
            o.x = f2bf(v.x); o.y = f2bf(v.y); o.z = f2bf(v.z); o.w = f2bf(v.w);
            *reinterpret_cast<ushort4*>(y + (size_t)i * 4) = o;
        }
        return;
    }
    bx -= 2 * nbCast;
    {
        // ---- W transposes (bf16, order Wgcn, Wr, Wl, Wgin) ----
        int w = bx >> 8;
        int i = ((bx & 255) << 8) + threadIdx.x;
        const float* W = (w == 0) ? W0 : (w == 1) ? W1 : (w == 2) ? W2 : W3;
        int c = i >> 8, k = i & 255;
        Wt[(size_t)w * D * D + i] = f2bf(W[k * D + c]);
    }
}

// --------------------------------------------------------------- scans
__device__ __forceinline__ unsigned hist_get(const unsigned* __restrict__ bh,
                                             int Nw, int nbH, int t, int b, int d)
{
    unsigned w = bh[(size_t)(t * nbH + b) * Nw + (d >> 1)];
    return (w >> ((d & 1) * 16)) & 0xFFFFu;
}

__global__ __launch_bounds__(256)
void k_scan_tile(const unsigned* __restrict__ blockhist, int* __restrict__ rows,
                 int* __restrict__ partials, int N, int TPT, int nbH)
{
    int t = blockIdx.y, tile = blockIdx.x;
    int i = tile * 256 + threadIdx.x;
    const int Nw = (N + 1) >> 1;
    __shared__ int sh[256];
    int v = 0;
    if (i < N)
        for (int b = 0; b < nbH; ++b) v += (int)hist_get(blockhist, Nw, nbH, t, b, i);
    sh[threadIdx.x] = v;
    __syncthreads();
#pragma unroll
    for (int off = 1; off < 256; off <<= 1) {
        int add = (threadIdx.x >= off) ? sh[threadIdx.x - off] : 0;
        __syncthreads();
        sh[threadIdx.x] += add;
        __syncthreads();
    }
    if (i < N) rows[(size_t)t * (N + 1) + i] = sh[threadIdx.x] - v;
    if (threadIdx.x == 255) partials[t * TPT + tile] = sh[255];
}

// finalize rows (per-thread prefix over tile partials -- scan_part folded in);
// emit per-(block,bin) ABSOLUTE i32 bases rel32 = rows+prefix
__global__ void k_scan_final(int* __restrict__ rows, const int* __restrict__ partials,
                             const unsigned* __restrict__ blockhist,
                             int* __restrict__ rel32,
                             int N, int TPT, int nbH, int E)
{
    int i = blockIdx.x * 256 + threadIdx.x;
    if (i >= 3 * N) return;
    int t = i / N, j = i - t * N;
    const int Nw = (N + 1) >> 1;
    int tile = j >> 8;
    int toff = 0;
    for (int tt = 0; tt < tile; ++tt) toff += partials[t * TPT + tt];
    int run = rows[(size_t)t * (N + 1) + j] + toff;
    rows[(size_t)t * (N + 1) + j] = run;
    if (j == 0) rows[(size_t)t * (N + 1) + N] = E;
    int acc = run;
    for (int b = 0; b < nbH; ++b) {
        rel32[(size_t)(t * nbH + b) * N + j] = acc;
        acc += (int)hist_get(blockhist, Nw, nbH, t, b, j);
    }
}

// ============ k_mid: proj GEMM blocks then scatter blocks (one launch)
__global__ __launch_bounds__(256)
void k_mid(const unsigned short* __restrict__ xbg,
           const unsigned short* __restrict__ xbi,
           const unsigned short* __restrict__ Wt,
           const float* __restrict__ br, const float* __restrict__ bl,
           unsigned short* __restrict__ xw, unsigned short* __restrict__ hr,
           unsigned short* __restrict__ hl,
           const int* __restrict__ ei_gg, const int* __restrict__ ei_ig,
           const int* __restrict__ ei_gi, const float* __restrict__ ew_gg,
           const float* __restrict__ ea_ig,
           const int* __restrict__ rel32, const unsigned short* __restrict__ rank16,
           int2* __restrict__ pk_gcn, int2* __restrict__ pk_gat,
           int* __restrict__ src_gin,
           int nbProj, int nbE, int nbH, int E, int N, int M)
{
    int bx = blockIdx.x;
    if (bx < nbProj) {
        // ----------------------------- proj GEMM --------------------------
        int brow = bx / 12;
        int yy   = bx - brow * 12;
        const int lane = threadIdx.x & 63;
        const int wave = threadIdx.x >> 6;
        const int lr = lane & 15;
        const int lk = lane >> 4;
        const int row0 = brow * 256 + wave * 64;

        const unsigned short* A;
        const unsigned short* Bt0;
        int col0;
        if (yy < 8) { A = xbg; Bt0 = Wt;             col0 = yy * 64; }
        else        { A = xbi; Bt0 = Wt + 2 * D * D; col0 = (yy - 8) * 64; }

        const unsigned short* ap[4];
#pragma unroll
        for (int rf = 0; rf < 4; ++rf) {
            int arow = row0 + rf * 16 + lr;
            int arow_c = (arow < M) ? arow : (M - 1);
            ap[rf] = A + (size_t)arow_c * D + lk * 8;
        }
        const unsigned short* bp = Bt0 + (size_t)(col0 + lr) * D + lk * 8;

        f32x4v acc[4][4] = {};
#pragma unroll
        for (int k0 = 0; k0 < 256; k0 += 32) {
            short8 af[4], bf[4];
#pragma unroll
            for (int rf = 0; rf < 4; ++rf)
                af[rf] = *reinterpret_cast<const short8*>(ap[rf] + k0);
#pragma unroll
            for (int nf = 0; nf < 4; ++nf)
                bf[nf] = *reinterpret_cast<const short8*>(bp + (size_t)nf * 16 * D + k0);
#pragma unroll
            for (int rf = 0; rf < 4; ++rf)
#pragma unroll
                for (int nf = 0; nf < 4; ++nf)
                    acc[rf][nf] = __builtin_amdgcn_mfma_f32_16x16x32_bf16(
                        af[rf], bf[nf], acc[rf][nf], 0, 0, 0);
        }

#pragma unroll
        for (int nf = 0; nf < 4; ++nf) {
            int c = col0 + nf * 16 + lr;
            unsigned short* dst;
            int cc;
            float bv;
            if (yy < 8) {
                if (c < 256) { dst = xw; cc = c;       bv = 0.f;    }
                else         { dst = hr; cc = c - 256; bv = br[cc]; }
            } else           { dst = hl; cc = c;       bv = bl[cc]; }
#pragma unroll
            for (int rf = 0; rf < 4; ++rf) {
#pragma unroll
                for (int i = 0; i < 4; ++i) {
                    int r = row0 + rf * 16 + 4 * lk + i;
                    if (r < M)
                        dst[(size_t)r * D + cc] = f2bf(acc[rf][nf][i] + bv);
                }
            }
        }
        return;
    }
    // ------------------- scatter: ONE random 4B read (rel32) per edge ------
    int sx = bx - nbProj;
    int t = sx / nbE;
    int blk = sx - t * nbE;
    int e = blk * 256 + threadIdx.x;
    if (e >= E) return;
    int b = e >> EPB_LOG;
    const int* rel = rel32 + (size_t)(t * nbH + b) * N;
    if (t == 0) {
        int s = ei_gg[e], d = ei_gg[E + e];
        int pos = rel[d] + (int)rank16[e];
        pk_gcn[pos] = make_int2(s, __float_as_int(ew_gg[e]));
    } else if (t == 1) {
        int s = ei_ig[e], d = ei_ig[E + e];
        int pos = rel[d] + (int)rank16[(size_t)E + e];
        pk_gat[pos] = make_int2(s, __float_as_int(ea_ig[e]));
    } else {
        int s = ei_gi[e], d = ei_gi[E + e];
        int pos = rel[d] + (int)rank16[2 * (size_t)E + e];
        src_gin[pos] = s;
    }
}

// ---------- dinv from CSR values: dinv[d] = rsqrt(1 + sum of incoming ew)
__global__ void k_deg(const int* __restrict__ rows, const int2* __restrict__ pk,
                      float* __restrict__ dinv, int N)
{
    int d = blockIdx.x * 256 + threadIdx.x;
    if (d >= N) return;
    float s = 1.0f;
    int p1 = rows[d + 1];
    for (int p = rows[d]; p < p1; ++p) s += __int_as_float(pk[p].y);
    dinv[d] = rsqrtf(s);
}

// ------------------------------------- GIN GEMM + fused LayerNorm + ReLU
__global__ __launch_bounds__(256)
void k_gin_gemm_ln(const unsigned short* __restrict__ A,
                   const unsigned short* __restrict__ Bt,
                   const float* __restrict__ bias,
                   const float* __restrict__ gamma, const float* __restrict__ beta,
                   float* __restrict__ out, int M)
{
    __shared__ float lds_s[4][64];
    __shared__ float lds_q[4][64];
    const int lane = threadIdx.x & 63;
    const int wave = threadIdx.x >> 6;
    const int lr = lane & 15;
    const int lk = lane >> 4;
    const int row0 = blockIdx.x * 64;
    const int col0 = wave * 64;

    const unsigned short* ap[4];
#pragma unroll
    for (int rf = 0; rf < 4; ++rf) {
        int arow = row0 + rf * 16 + lr;
        int arow_c = (arow < M) ? arow : (M - 1);
        ap[rf] = A + (size_t)arow_c * D + lk * 8;
    }
    const unsigned short* bp = Bt + (size_t)(col0 + lr) * D + lk * 8;

    f32x4v acc[4][4] = {};
#pragma unroll
    for (int k0 = 0; k0 < 256; k0 += 32) {
        short8 af[4], bf[4];
#pragma unroll
        for (int rf = 0; rf < 4; ++rf)
            af[rf] = *reinterpret_cast<const short8*>(ap[rf] + k0);
#pragma unroll
        for (int nf = 0; nf < 4; ++nf)
            bf[nf] = *reinterpret_cast<const short8*>(bp + (size_t)nf * 16 * D + k0);
#pragma unroll
        for (int rf = 0; rf < 4; ++rf)
#pragma unroll
            for (int nf = 0; nf < 4; ++nf)
                acc[rf][nf] = __builtin_amdgcn_mfma_f32_16x16x32_bf16(
                    af[rf], bf[nf], acc[rf][nf], 0, 0, 0);
    }

    float bv[4], gv[4], be[4];
#pragma unroll
    for (int nf = 0; nf < 4; ++nf) {
        int c = col0 + nf * 16 + lr;
        bv[nf] = bias[c]; gv[nf] = gamma[c]; be[nf] = beta[c];
    }

#pragma unroll
    for (int rf = 0; rf < 4; ++rf) {
        float ps[4], pq[4];
#pragma unroll
        for (int i = 0; i < 4; ++i) {
            float s = 0.f, q = 0.f;
#pragma unroll
            for (int nf = 0; nf < 4; ++nf) {
                float v = acc[rf][nf][i] + bv[nf];
                acc[rf][nf][i] = v;
                s += v; q += v * v;
            }
            ps[i] = s; pq[i] = q;
        }
#pragma unroll
        for (int off = 1; off < 16; off <<= 1) {
#pragma unroll
            for (int i = 0; i < 4; ++i) {
                ps[i] += __shfl_xor(ps[i], off, 64);
                pq[i] += __shfl_xor(pq[i], off, 64);
            }
        }
        if (lr == 0) {
#pragma unroll
            for (int i = 0; i < 4; ++i) {
                lds_s[wave][rf * 16 + lk * 4 + i] = ps[i];
                lds_q[wave][rf * 16 + lk * 4 + i] = pq[i];
            }
        }
    }
    __syncthreads();

#pragma unroll
    for (int rf = 0; rf < 4; ++rf) {
#pragma unroll
        for (int i = 0; i < 4; ++i) {
            int rl = rf * 16 + 4 * lk + i;
            float s = lds_s[0][rl] + lds_s[1][rl] + lds_s[2][rl] + lds_s[3][rl];
            float q = lds_q[0][rl] + lds_q[1][rl] + lds_q[2][rl] + lds_q[3][rl];
            float mu  = s * (1.0f / 256.0f);
            float var = q * (1.0f / 256.0f) - mu * mu;
            float rs  = rsqrtf(var + 1e-5f);
            int r = row0 + rl;
            if (r < M) {
#pragma unroll
                for (int nf = 0; nf < 4; ++nf) {
                    out[(size_t)r * D + col0 + nf * 16 + lr] =
                        fmaxf(0.f, (acc[rf][nf][i] - mu) * rs * gv[nf] + be[nf]);
                }
            }
        }
    }
}

// ================== fused gather (full-wave): glom GCN+GATv2+LN, GIN agg
__global__ __launch_bounds__(256)
void k_gather_fused(const unsigned short* __restrict__ xw,
                    const unsigned short* __restrict__ hl,
                    const unsigned short* __restrict__ hr,
                    const float* __restrict__ dinv,
                    const int* __restrict__ rows_gcn, const int2* __restrict__ pk_gcn,
                    const int* __restrict__ rows_gat, const int2* __restrict__ pk_gat,
                    const float* __restrict__ We, const float* __restrict__ att,
                    const float* __restrict__ b_gcn, const float* __restrict__ b_gat,
                    const float* __restrict__ gamma, const float* __restrict__ beta,
                    float* __restrict__ glom_out,
                    const unsigned short* __restrict__ xb_glom,
                    const unsigned short* __restrict__ xb_imm,
                    const float* __restrict__ eps,
                    const int* __restrict__ rows_gin, const int* __restrict__ src_gin,
                    unsigned short* __restrict__ agg,
                    int N)
{
    int gw   = __builtin_amdgcn_readfirstlane((blockIdx.x * 256 + threadIdx.x) >> 6);
    int lane = threadIdx.x & 63;

    if (gw < N) {
        // ------------------------------ glom path -------------------------
        int node = gw;
        float4 We4  = ld4(&We[lane * 4]);
        float4 att4 = ld4(&att[lane * 4]);
        float4 hrv  = ldb4(&hr[(size_t)node * D + lane * 4]);

        float di = dinv[node];
        float4 acc = ldb4(&xw[(size_t)node * D + lane * 4]);
        float4 g0  = ld4(&b_gcn[lane * 4]);
        float4 a0  = ld4(&b_gat[lane * 4]);
        float sc0 = di * di;
        acc.x = sc0 * acc.x + g0.x + a0.x;
        acc.y = sc0 * acc.y + g0.y + a0.y;
        acc.z = sc0 * acc.z + g0.z + a0.z;
        acc.w = sc0 * acc.w + g0.w + a0.w;

        // ---- GCN neighbor sum, 4 edges in flight; coef = w*dinv[s]*di ----
        int p  = rows_gcn[node];
        int p1 = rows_gcn[node + 1];
        for (; p + 4 <= p1; p += 4) {
            int2  pk[4];
            float cf[4];
            float4 v[4];
#pragma unroll
            for (int j = 0; j < 4; ++j) pk[j] = pk_gcn[p + j];
#pragma unroll
            for (int j = 0; j < 4; ++j)
                cf[j] = __int_as_float(pk[j].y) * dinv[pk[j].x] * di;
#pragma unroll
            for (int j = 0; j < 4; ++j) v[j] = ldb4(&xw[(size_t)pk[j].x * D + lane * 4]);
#pragma unroll
            for (int j = 0; j < 4; ++j) {
                acc.x += cf[j] * v[j].x; acc.y += cf[j] * v[j].y;
                acc.z += cf[j] * v[j].z; acc.w += cf[j] * v[j].w;
            }
        }
        for (; p < p1; ++p) {
            int2 pk = pk_gcn[p];
            float cx = __int_as_float(pk.y) * dinv[pk.x] * di;
            float4 v = ldb4(&xw[(size_t)pk.x * D + lane * 4]);
            acc.x += cx * v.x; acc.y += cx * v.y;
            acc.z += cx * v.z; acc.w += cx * v.w;
        }

        // ---- GATv2: unnormalized exp (logits bounded), 4 edges in flight --
        int q  = rows_gat[node];
        int q1 = rows_gat[node + 1];
        int has = (q1 > q);
        float den = 0.f;
        float4 ag = make_float4(0.f, 0.f, 0.f, 0.f);
        for (; q + 4 <= q1; q += 4) {
            int2  pk[4];
            float4 h[4];
            float pp[4];
#pragma unroll
            for (int j = 0; j < 4; ++j) pk[j] = pk_gat[q + j];
#pragma unroll
            for (int j = 0; j < 4; ++j) h[j] = ldb4(&hl[(size_t)pk[j].x * D + lane * 4]);
#pragma unroll
            for (int j = 0; j < 4; ++j)
                pp[j] = wave_sum(gat_partial(h[j], hrv, __int_as_float(pk[j].y), We4, att4));
            float x[4];
#pragma unroll
            for (int j = 0; j < 4; ++j) x[j] = __expf(pp[j]);
            den += (x[0] + x[1]) + (x[2] + x[3]);
#pragma unroll
            for (int j = 0; j < 4; ++j) {
                ag.x += x[j] * h[j].x; ag.y += x[j] * h[j].y;
                ag.z += x[j] * h[j].z; ag.w += x[j] * h[j].w;
            }
        }
        for (; q < q1; ++q) {
            int2 pk = pk_gat[q];
            float4 h = ldb4(&hl[(size_t)pk.x * D + lane * 4]);
            float pp = wave_sum(gat_partial(h, hrv, __int_as_float(pk.y), We4, att4));
            float x = __expf(pp);
            den += x;
            ag.x += x * h.x; ag.y += x * h.y;
            ag.z += x * h.z; ag.w += x * h.w;
        }
        if (has) {
            float inv = 1.0f / den;
            acc.x += ag.x * inv; acc.y += ag.y * inv;
            acc.z += ag.z * inv; acc.w += ag.w * inv;
        }

        // ---- LayerNorm + ReLU ----
        float s_ = acc.x + acc.y + acc.z + acc.w;
        float sq = acc.x * acc.x + acc.y * acc.y + acc.z * acc.z + acc.w * acc.w;
#pragma unroll
        for (int off = 32; off > 0; off >>= 1) {
            s_ += __shfl_xor(s_, off, 64);
            sq += __shfl_xor(sq, off, 64);
        }
        float mu  = s_ * (1.0f / 256.0f);
        float var = sq * (1.0f / 256.0f) - mu * mu;
        float rs  = rsqrtf(var + 1e-5f);
        float4 g = ld4(&gamma[lane * 4]);
        float4 b = ld4(&beta[lane * 4]);
        float4 o;
        o.x = fmaxf(0.f, (acc.x - mu) * rs * g.x + b.x);
        o.y = fmaxf(0.f, (acc.y - mu) * rs * g.y + b.y);
        o.z = fmaxf(0.f, (acc.z - mu) * rs * g.z + b.z);
        o.w = fmaxf(0.f, (acc.w - mu) * rs * g.w + b.w);
        st4(&glom_out[(size_t)node * D + lane * 4], o);
    } else if (gw < 2 * N) {
        // ------------------------------ gin path --------------------------
        int node = gw - N;
        float c = 1.0f + eps[0];
        float4 acc = ldb4(&xb_imm[(size_t)node * D + lane * 4]);
        acc.x *= c; acc.y *= c; acc.z *= c; acc.w *= c;
        int p  = rows_gin[node];
        int p1 = rows_gin[node + 1];
        for (; p + 4 <= p1; p += 4) {
            int s[4];
            float4 v[4];
#pragma unroll
            for (int j = 0; j < 4; ++j) s[j] = src_gin[p + j];
#pragma unroll
            for (int j = 0; j < 4; ++j) v[j] = ldb4(&xb_glom[(size_t)s[j] * D + lane * 4]);
            acc.x += (v[0].x + v[1].x) + (v[2].x + v[3].x);
            acc.y += (v[0].y + v[1].y) + (v[2].y + v[3].y);
            acc.z += (v[0].z + v[1].z) + (v[2].z + v[3].z);
            acc.w += (v[0].w + v[1].w) + (v[2].w + v[3].w);
        }
        for (; p < p1; ++p) {
            int sx = src_gin[p];
            float4 v = ldb4(&xb_glom[(size_t)sx * D + lane * 4]);
            acc.x += v.x; acc.y += v.y; acc.z += v.z; acc.w += v.w;
        }
        ushort4 o;
        o.x = f2bf(acc.x); o.y = f2bf(acc.y); o.z = f2bf(acc.z); o.w = f2bf(acc.w);
        *reinterpret_cast<ushort4*>(agg + (size_t)node * D + lane * 4) = o;
    }
}

// ------------------------------------------------------------------ launch
extern "C" void kernel_launch(void* const* d_in, const int* in_sizes, int n_in,
                              void* d_out, int out_size, void* d_ws, size_t ws_size,
                              hipStream_t stream)
{
    const float* x_glom = (const float*)d_in[0];
    const float* x_imm  = (const float*)d_in[1];
    const float* ew_gg  = (const float*)d_in[2];
    const float* ea_ig  = (const float*)d_in[3];
    const float* W_gcn  = (const float*)d_in[4];
    const float* b_gcn  = (const float*)d_in[5];
    const float* Wl     = (const float*)d_in[6];
    const float* bl     = (const float*)d_in[7];
    const float* Wr     = (const float*)d_in[8];
    const float* br     = (const float*)d_in[9];
    const float* att    = (const float*)d_in[10];
    const float* We     = (const float*)d_in[11];
    const float* b_gat  = (const float*)d_in[12];
    const float* eps    = (const float*)d_in[13];
    const float* W_gin  = (const float*)d_in[14];
    const float* b_gin  = (const float*)d_in[15];
    const float* gamma  = (const float*)d_in[16];
    const float* beta   = (const float*)d_in[17];
    const int*   ei_gg  = (const int*)d_in[18];
    const int*   ei_ig  = (const int*)d_in[19];
    const int*   ei_gi  = (const int*)d_in[20];

    const int N = in_sizes[0] / D;     // 20000
    const int E = in_sizes[2];         // 320000
    const size_t ND = (size_t)N * D;
    const int TPT = (N + 255) / 256;
    const int nbH = (E + EPB - 1) / EPB;       // hist blocks per type (79)

    // ---- workspace layout ----
    char* base = (char*)d_ws;
    size_t off = 0;
    auto alloc = [&](size_t bytes) {
        void* p = base + off;
        off = (off + bytes + 255) & ~(size_t)255;
        return p;
    };
    unsigned short* xb_glom = (unsigned short*)alloc(ND * 2);
    unsigned short* xb_imm  = (unsigned short*)alloc(ND * 2);
    unsigned short* xw_b    = (unsigned short*)alloc(ND * 2);
    unsigned short* hl_b    = (unsigned short*)alloc(ND * 2);
    unsigned short* hr_b    = (unsigned short*)alloc(ND * 2);
    unsigned short* agg_b   = (unsigned short*)alloc(ND * 2);   // aliases blockhist
    unsigned*       blockhist = (unsigned*)agg_b;               // dead before gather
    unsigned short* Wt      = (unsigned short*)alloc(4 * D * D * 2);
    float* dinv    = (float*)alloc((size_t)N * 4);
    int*   rows    = (int*)alloc(3 * (size_t)(N + 1) * 4);
    int*   parts   = (int*)alloc(3 * (size_t)TPT * 4);
    int*   rel32   = (int*)alloc(3 * (size_t)nbH * N * 4);
    unsigned short* rank16 = (unsigned short*)alloc(3 * (size_t)E * 2);
    int2*  pk_gcn  = (int2*)alloc((size_t)E * 8);
    int2*  pk_gat  = (int2*)alloc((size_t)E * 8);
    int*   src_gin = (int*)alloc((size_t)E * 4);

    float* glom_out = (float*)d_out;
    float* imm_out  = (float*)d_out + ND;

    const int n4      = (int)(ND / 4);
    const int nbCast  = (n4 + 255) / 256;          // 5000
    const int nbE     = (E + 255) / 256;           // 1250 scatter blocks/type
    const int nb_3n   = (3 * N + 255) / 256;
    const int nb_2nw  = (2 * N + 3) / 4;
    const int nbProj  = ((N + 255) / 256) * 12;    // 948

    // 1. front: LDS hist (no global atomics) || casts || W transposes
    k_front<<<3 * nbH + 2 * nbCast + 1024, 256, 0, stream>>>(
        x_glom, x_imm, xb_glom, xb_imm,
        W_gcn, Wr, Wl, W_gin, Wt,
        ei_gg, ei_ig, ei_gi,
        blockhist, rank16, n4, nbCast, nbH, E, N);
    // 2-3. scans (scan_part folded into scan_final)
    k_scan_tile<<<dim3(TPT, 3), 256, 0, stream>>>(blockhist, rows, parts, N, TPT, nbH);
    k_scan_final<<<nb_3n, 256, 0, stream>>>(rows, parts, blockhist, rel32,
                                            N, TPT, nbH, E);
    // 4. mid: proj GEMM || scatter (1 random read/edge)
    k_mid<<<nbProj + 3 * nbE, 256, 0, stream>>>(
        xb_glom, xb_imm, Wt, br, bl, xw_b, hr_b, hl_b,
        ei_gg, ei_ig, ei_gi, ew_gg, ea_ig,
        rel32, rank16, pk_gcn, pk_gat, src_gin,
        nbProj, nbE, nbH, E, N, N);
    // 5. dinv from CSR values
    k_deg<<<(N + 255) / 256, 256, 0, stream>>>(rows, pk_gcn, dinv, N);
    // 6. fused gathers (full-wave)
    k_gather_fused<<<nb_2nw, 256, 0, stream>>>(
        xw_b, hl_b, hr_b, dinv,
        rows, pk_gcn,
        rows + (N + 1), pk_gat,
        We, att, b_gcn, b_gat, gamma, beta, glom_out,
        xb_glom, xb_imm, eps,
        rows + 2 * (N + 1), src_gin, agg_b, N);
    // 7. GIN GEMM + fused LN + ReLU
    k_gin_gemm_ln<<<(N + 63) / 64, 256, 0, stream>>>(
        agg_b, Wt + 3 * D * D, b_gin, gamma, beta, imm_out, N);
}

// Round 18
// 211.314 us; speedup vs baseline: 1.1355x; 1.0908x over previous
//
#include <hip/hip_runtime.h>

// HeteroMessagePassingLayer Round 18:
//  - R17 structure, EPB 4096 -> 8192: halves rel32 (19->9.5MB, L2-resident
//    for scatter's random read), halves scan inner loops (79->40 blocks)
//  - everything else identical to R17

constexpr int D = 256;
constexpr int EPB_LOG = 13;                 // 8192 edges per hist block
constexpr int EPB = 1 << EPB_LOG;
constexpr int MAXW = 10240;                 // LDS hist words (N<=20480)

typedef __attribute__((ext_vector_type(4))) float f32x4v;
typedef __attribute__((ext_vector_type(8))) short short8;

// ---------------------------------------------------------------- utilities
__device__ __forceinline__ float4 ld4(const float* p) {
    return *reinterpret_cast<const float4*>(p);
}
__device__ __forceinline__ void st4(float* p, float4 v) {
    *reinterpret_cast<float4*>(p) = v;
}
__device__ __forceinline__ unsigned short f2bf(float f) {
    unsigned u = __float_as_uint(f);
    u = u + 0x7FFFu + ((u >> 16) & 1u);
    return (unsigned short)(u >> 16);
}
__device__ __forceinline__ float bf2f(unsigned short u) {
    return __uint_as_float(((unsigned)u) << 16);
}
__device__ __forceinline__ float4 ldb4(const unsigned short* p) {
    ushort4 u = *reinterpret_cast<const ushort4*>(p);
    return make_float4(bf2f(u.x), bf2f(u.y), bf2f(u.z), bf2f(u.w));
}
__device__ __forceinline__ float wave_sum(float p) {
#pragma unroll
    for (int off = 32; off > 0; off >>= 1) p += __shfl_xor(p, off, 64);
    return p;
}
__device__ __forceinline__ float gat_partial(float4 h, float4 hrv, float ea,
                                             float4 We4, float4 att4) {
    float z, pp = 0.f;
    z = h.x + hrv.x + ea * We4.x; z *= (z > 0.f) ? 1.0f : 0.2f; pp += z * att4.x;
    z = h.y + hrv.y + ea * We4.y; z *= (z > 0.f) ? 1.0f : 0.2f; pp += z * att4.y;
    z = h.z + hrv.z + ea * We4.z; z *= (z > 0.f) ? 1.0f : 0.2f; pp += z * att4.z;
    z = h.w + hrv.w + ea * We4.w; z *= (z > 0.f) ? 1.0f : 0.2f; pp += z * att4.w;
    return pp;
}

// ============ k_front: LDS hist blocks FIRST, then casts, then W transposes
__global__ __launch_bounds__(256)
void k_front(const float* __restrict__ x_glom, const float* __restrict__ x_imm,
             unsigned short* __restrict__ xb_glom, unsigned short* __restrict__ xb_imm,
             const float* __restrict__ W0, const float* __restrict__ W1,
             const float* __restrict__ W2, const float* __restrict__ W3,
             unsigned short* __restrict__ Wt,
             const int* __restrict__ ei_gg, const int* __restrict__ ei_ig,
             const int* __restrict__ ei_gi,
             unsigned* __restrict__ blockhist, unsigned short* __restrict__ rank16,
             int n4, int nbCast, int nbH, int E, int N)
{
    __shared__ unsigned ldsh[MAXW];
    int bx = blockIdx.x;
    if (bx < 3 * nbH) {
        // ---- LDS histogram: counts + local rank ----
        int t = bx / nbH;
        int b = bx - t * nbH;
        const int* ei = (t == 0) ? ei_gg : (t == 1) ? ei_ig : ei_gi;
        const int Nw = (N + 1) >> 1;
        for (int w = threadIdx.x; w < Nw; w += 256) ldsh[w] = 0u;
        __syncthreads();
        int e0 = b << EPB_LOG;
#pragma unroll
        for (int it = 0; it < EPB / 256; ++it) {
            int e = e0 + it * 256 + threadIdx.x;
            if (e < E) {
                int d = ei[E + e];
                unsigned sh = (d & 1) * 16;
                unsigned old = atomicAdd(&ldsh[d >> 1], 1u << sh);
                rank16[(size_t)t * E + e] = (unsigned short)((old >> sh) & 0xFFFFu);
            }
        }
        __syncthreads();
        unsigned* dst = blockhist + (size_t)(t * nbH + b) * Nw;
        for (int w = threadIdx.x; w < Nw; w += 256) dst[w] = ldsh[w];
        return;
    }
    bx -= 3 * nbH;
    if (bx < 2 * nbCast) {
        // ---- casts ----
        bool second = (bx >= nbCast);
        int i = (second ? bx - nbCast : bx) * 256 + threadIdx.x;
        if (i < n4) {
            const float* x = second ? x_imm : x_glom;
            unsigned short* y = second ? xb_imm : xb_glom;
            float4 v = ld4(x + (size_t)i * 4);
            ushort4 o;
            o.x = f2bf(v.x); o.y = f2bf(v.y); o.z = f2bf(v.z); o.w = f2bf(v.w);
            *reinterpret_cast<ushort4*>(y + (size_t)i * 4) = o;
        }
        return;
    }
    bx -= 2 * nbCast;
    {
        // ---- W transposes (bf16, order Wgcn, Wr, Wl, Wgin) ----
        int w = bx >> 8;
        int i = ((bx & 255) << 8) + threadIdx.x;
        const float* W = (w == 0) ? W0 : (w == 1) ? W1 : (w == 2) ? W2 : W3;
        int c = i >> 8, k = i & 255;
        Wt[(size_t)w * D * D + i] = f2bf(W[k * D + c]);
    }
}

// --------------------------------------------------------------- scans
__device__ __forceinline__ unsigned hist_get(const unsigned* __restrict__ bh,
                                             int Nw, int nbH, int t, int b, int d)
{
    unsigned w = bh[(size_t)(t * nbH + b) * Nw + (d >> 1)];
    return (w >> ((d & 1) * 16)) & 0xFFFFu;
}

__global__ __launch_bounds__(256)
void k_scan_tile(const unsigned* __restrict__ blockhist, int* __restrict__ rows,
                 int* __restrict__ partials, int N, int TPT, int nbH)
{
    int t = blockIdx.y, tile = blockIdx.x;
    int i = tile * 256 + threadIdx.x;
    const int Nw = (N + 1) >> 1;
    __shared__ int sh[256];
    int v = 0;
    if (i < N)
        for (int b = 0; b < nbH; ++b) v += (int)hist_get(blockhist, Nw, nbH, t, b, i);
    sh[threadIdx.x] = v;
    __syncthreads();
#pragma unroll
    for (int off = 1; off < 256; off <<= 1) {
        int add = (threadIdx.x >= off) ? sh[threadIdx.x - off] : 0;
        __syncthreads();
        sh[threadIdx.x] += add;
        __syncthreads();
    }
    if (i < N) rows[(size_t)t * (N + 1) + i] = sh[threadIdx.x] - v;
    if (threadIdx.x == 255) partials[t * TPT + tile] = sh[255];
}

// finalize rows (per-thread prefix over tile partials);
// emit per-(block,bin) ABSOLUTE i32 bases rel32 = rows+prefix
__global__ void k_scan_final(int* __restrict__ rows, const int* __restrict__ partials,
                             const unsigned* __restrict__ blockhist,
                             int* __restrict__ rel32,
                             int N, int TPT, int nbH, int E)
{
    int i = blockIdx.x * 256 + threadIdx.x;
    if (i >= 3 * N) return;
    int t = i / N, j = i - t * N;
    const int Nw = (N + 1) >> 1;
    int tile = j >> 8;
    int toff = 0;
    for (int tt = 0; tt < tile; ++tt) toff += partials[t * TPT + tt];
    int run = rows[(size_t)t * (N + 1) + j] + toff;
    rows[(size_t)t * (N + 1) + j] = run;
    if (j == 0) rows[(size_t)t * (N + 1) + N] = E;
    int acc = run;
    for (int b = 0; b < nbH; ++b) {
        rel32[(size_t)(t * nbH + b) * N + j] = acc;
        acc += (int)hist_get(blockhist, Nw, nbH, t, b, j);
    }
}

// ============ k_mid: proj GEMM blocks then scatter blocks (one launch)
__global__ __launch_bounds__(256)
void k_mid(const unsigned short* __restrict__ xbg,
           const unsigned short* __restrict__ xbi,
           const unsigned short* __restrict__ Wt,
           const float* __restrict__ br, const float* __restrict__ bl,
           unsigned short* __restrict__ xw, unsigned short* __restrict__ hr,
           unsigned short* __restrict__ hl,
           const int* __restrict__ ei_gg, const int* __restrict__ ei_ig,
           const int* __restrict__ ei_gi, const float* __restrict__ ew_gg,
           const float* __restrict__ ea_ig,
           const int* __restrict__ rel32, const unsigned short* __restrict__ rank16,
           int2* __restrict__ pk_gcn, int2* __restrict__ pk_gat,
           int* __restrict__ src_gin,
           int nbProj, int nbE, int nbH, int E, int N, int M)
{
    int bx = blockIdx.x;
    if (bx < nbProj) {
        // ----------------------------- proj GEMM --------------------------
        int brow = bx / 12;
        int yy   = bx - brow * 12;
        const int lane = threadIdx.x & 63;
        const int wave = threadIdx.x >> 6;
        const int lr = lane & 15;
        const int lk = lane >> 4;
        const int row0 = brow * 256 + wave * 64;

        const unsigned short* A;
        const unsigned short* Bt0;
        int col0;
        if (yy < 8) { A = xbg; Bt0 = Wt;             col0 = yy * 64; }
        else        { A = xbi; Bt0 = Wt + 2 * D * D; col0 = (yy - 8) * 64; }

        const unsigned short* ap[4];
#pragma unroll
        for (int rf = 0; rf < 4; ++rf) {
            int arow = row0 + rf * 16 + lr;
            int arow_c = (arow < M) ? arow : (M - 1);
            ap[rf] = A + (size_t)arow_c * D + lk * 8;
        }
        const unsigned short* bp = Bt0 + (size_t)(col0 + lr) * D + lk * 8;

        f32x4v acc[4][4] = {};
#pragma unroll
        for (int k0 = 0; k0 < 256; k0 += 32) {
            short8 af[4], bf[4];
#pragma unroll
            for (int rf = 0; rf < 4; ++rf)
                af[rf] = *reinterpret_cast<const short8*>(ap[rf] + k0);
#pragma unroll
            for (int nf = 0; nf < 4; ++nf)
                bf[nf] = *reinterpret_cast<const short8*>(bp + (size_t)nf * 16 * D + k0);
#pragma unroll
            for (int rf = 0; rf < 4; ++rf)
#pragma unroll
                for (int nf = 0; nf < 4; ++nf)
                    acc[rf][nf] = __builtin_amdgcn_mfma_f32_16x16x32_bf16(
                        af[rf], bf[nf], acc[rf][nf], 0, 0, 0);
        }

#pragma unroll
        for (int nf = 0; nf < 4; ++nf) {
            int c = col0 + nf * 16 + lr;
            unsigned short* dst;
            int cc;
            float bv;
            if (yy < 8) {
                if (c < 256) { dst = xw; cc = c;       bv = 0.f;    }
                else         { dst = hr; cc = c - 256; bv = br[cc]; }
            } else           { dst = hl; cc = c;       bv = bl[cc]; }
#pragma unroll
            for (int rf = 0; rf < 4; ++rf) {
#pragma unroll
                for (int i = 0; i < 4; ++i) {
                    int r = row0 + rf * 16 + 4 * lk + i;
                    if (r < M)
                        dst[(size_t)r * D + cc] = f2bf(acc[rf][nf][i] + bv);
                }
            }
        }
        return;
    }
    // ------------------- scatter: ONE random 4B read (rel32) per edge ------
    int sx = bx - nbProj;
    int t = sx / nbE;
    int blk = sx - t * nbE;
    int e = blk * 256 + threadIdx.x;
    if (e >= E) return;
    int b = e >> EPB_LOG;
    const int* rel = rel32 + (size_t)(t * nbH + b) * N;
    if (t == 0) {
        int s = ei_gg[e], d = ei_gg[E + e];
        int pos = rel[d] + (int)rank16[e];
        pk_gcn[pos] = make_int2(s, __float_as_int(ew_gg[e]));
    } else if (t == 1) {
        int s = ei_ig[e], d = ei_ig[E + e];
        int pos = rel[d] + (int)rank16[(size_t)E + e];
        pk_gat[pos] = make_int2(s, __float_as_int(ea_ig[e]));
    } else {
        int s = ei_gi[e], d = ei_gi[E + e];
        int pos = rel[d] + (int)rank16[2 * (size_t)E + e];
        src_gin[pos] = s;
    }
}

// ---------- dinv from CSR values: dinv[d] = rsqrt(1 + sum of incoming ew)
__global__ void k_deg(const int* __restrict__ rows, const int2* __restrict__ pk,
                      float* __restrict__ dinv, int N)
{
    int d = blockIdx.x * 256 + threadIdx.x;
    if (d >= N) return;
    float s = 1.0f;
    int p1 = rows[d + 1];
    for (int p = rows[d]; p < p1; ++p) s += __int_as_float(pk[p].y);
    dinv[d] = rsqrtf(s);
}

// ------------------------------------- GIN GEMM + fused LayerNorm + ReLU
__global__ __launch_bounds__(256)
void k_gin_gemm_ln(const unsigned short* __restrict__ A,
                   const unsigned short* __restrict__ Bt,
                   const float* __restrict__ bias,
                   const float* __restrict__ gamma, const float* __restrict__ beta,
                   float* __restrict__ out, int M)
{
    __shared__ float lds_s[4][64];
    __shared__ float lds_q[4][64];
    const int lane = threadIdx.x & 63;
    const int wave = threadIdx.x >> 6;
    const int lr = lane & 15;
    const int lk = lane >> 4;
    const int row0 = blockIdx.x * 64;
    const int col0 = wave * 64;

    const unsigned short* ap[4];
#pragma unroll
    for (int rf = 0; rf < 4; ++rf) {
        int arow = row0 + rf * 16 + lr;
        int arow_c = (arow < M) ? arow : (M - 1);
        ap[rf] = A + (size_t)arow_c * D + lk * 8;
    }
    const unsigned short* bp = Bt + (size_t)(col0 + lr) * D + lk * 8;

    f32x4v acc[4][4] = {};
#pragma unroll
    for (int k0 = 0; k0 < 256; k0 += 32) {
        short8 af[4], bf[4];
#pragma unroll
        for (int rf = 0; rf < 4; ++rf)
            af[rf] = *reinterpret_cast<const short8*>(ap[rf] + k0);
#pragma unroll
        for (int nf = 0; nf < 4; ++nf)
            bf[nf] = *reinterpret_cast<const short8*>(bp + (size_t)nf * 16 * D + k0);
#pragma unroll
        for (int rf = 0; rf < 4; ++rf)
#pragma unroll
            for (int nf = 0; nf < 4; ++nf)
                acc[rf][nf] = __builtin_amdgcn_mfma_f32_16x16x32_bf16(
                    af[rf], bf[nf], acc[rf][nf], 0, 0, 0);
    }

    float bv[4], gv[4], be[4];
#pragma unroll
    for (int nf = 0; nf < 4; ++nf) {
        int c = col0 + nf * 16 + lr;
        bv[nf] = bias[c]; gv[nf] = gamma[c]; be[nf] = beta[c];
    }

#pragma unroll
    for (int rf = 0; rf < 4; ++rf) {
        float ps[4], pq[4];
#pragma unroll
        for (int i = 0; i < 4; ++i) {
            float s = 0.f, q = 0.f;
#pragma unroll
            for (int nf = 0; nf < 4; ++nf) {
                float v = acc[rf][nf][i] + bv[nf];
                acc[rf][nf][i] = v;
                s += v; q += v * v;
            }
            ps[i] = s; pq[i] = q;
        }
#pragma unroll
        for (int off = 1; off < 16; off <<= 1) {
#pragma unroll
            for (int i = 0; i < 4; ++i) {
                ps[i] += __shfl_xor(ps[i], off, 64);
                pq[i] += __shfl_xor(pq[i], off, 64);
            }
        }
        if (lr == 0) {
#pragma unroll
            for (int i = 0; i < 4; ++i) {
                lds_s[wave][rf * 16 + lk * 4 + i] = ps[i];
                lds_q[wave][rf * 16 + lk * 4 + i] = pq[i];
            }
        }
    }
    __syncthreads();

#pragma unroll
    for (int rf = 0; rf < 4; ++rf) {
#pragma unroll
        for (int i = 0; i < 4; ++i) {
            int rl = rf * 16 + 4 * lk + i;
            float s = lds_s[0][rl] + lds_s[1][rl] + lds_s[2][rl] + lds_s[3][rl];
            float q = lds_q[0][rl] + lds_q[1][rl] + lds_q[2][rl] + lds_q[3][rl];
            float mu  = s * (1.0f / 256.0f);
            float var = q * (1.0f / 256.0f) - mu * mu;
            float rs  = rsqrtf(var + 1e-5f);
            int r = row0 + rl;
            if (r < M) {
#pragma unroll
                for (int nf = 0; nf < 4; ++nf) {
                    out[(size_t)r * D + col0 + nf * 16 + lr] =
                        fmaxf(0.f, (acc[rf][nf][i] - mu) * rs * gv[nf] + be[nf]);
                }
            }
        }
    }
}

// ================== fused gather (full-wave): glom GCN+GATv2+LN, GIN agg
__global__ __launch_bounds__(256)
void k_gather_fused(const unsigned short* __restrict__ xw,
                    const unsigned short* __restrict__ hl,
                    const unsigned short* __restrict__ hr,
                    const float* __restrict__ dinv,
                    const int* __restrict__ rows_gcn, const int2* __restrict__ pk_gcn,
                    const int* __restrict__ rows_gat, const int2* __restrict__ pk_gat,
                    const float* __restrict__ We, const float* __restrict__ att,
                    const float* __restrict__ b_gcn, const float* __restrict__ b_gat,
                    const float* __restrict__ gamma, const float* __restrict__ beta,
                    float* __restrict__ glom_out,
                    const unsigned short* __restrict__ xb_glom,
                    const unsigned short* __restrict__ xb_imm,
                    const float* __restrict__ eps,
                    const int* __restrict__ rows_gin, const int* __restrict__ src_gin,
                    unsigned short* __restrict__ agg,
                    int N)
{
    int gw   = __builtin_amdgcn_readfirstlane((blockIdx.x * 256 + threadIdx.x) >> 6);
    int lane = threadIdx.x & 63;

    if (gw < N) {
        // ------------------------------ glom path -------------------------
        int node = gw;
        float4 We4  = ld4(&We[lane * 4]);
        float4 att4 = ld4(&att[lane * 4]);
        float4 hrv  = ldb4(&hr[(size_t)node * D + lane * 4]);

        float di = dinv[node];
        float4 acc = ldb4(&xw[(size_t)node * D + lane * 4]);
        float4 g0  = ld4(&b_gcn[lane * 4]);
        float4 a0  = ld4(&b_gat[lane * 4]);
        float sc0 = di * di;
        acc.x = sc0 * acc.x + g0.x + a0.x;
        acc.y = sc0 * acc.y + g0.y + a0.y;
        acc.z = sc0 * acc.z + g0.z + a0.z;
        acc.w = sc0 * acc.w + g0.w + a0.w;

        // ---- GCN neighbor sum, 4 edges in flight; coef = w*dinv[s]*di ----
        int p  = rows_gcn[node];
        int p1 = rows_gcn[node + 1];
        for (; p + 4 <= p1; p += 4) {
            int2  pk[4];
            float cf[4];
            float4 v[4];
#pragma unroll
            for (int j = 0; j < 4; ++j) pk[j] = pk_gcn[p + j];
#pragma unroll
            for (int j = 0; j < 4; ++j)
                cf[j] = __int_as_float(pk[j].y) * dinv[pk[j].x] * di;
#pragma unroll
            for (int j = 0; j < 4; ++j) v[j] = ldb4(&xw[(size_t)pk[j].x * D + lane * 4]);
#pragma unroll
            for (int j = 0; j < 4; ++j) {
                acc.x += cf[j] * v[j].x; acc.y += cf[j] * v[j].y;
                acc.z += cf[j] * v[j].z; acc.w += cf[j] * v[j].w;
            }
        }
        for (; p < p1; ++p) {
            int2 pk = pk_gcn[p];
            float cx = __int_as_float(pk.y) * dinv[pk.x] * di;
            float4 v = ldb4(&xw[(size_t)pk.x * D + lane * 4]);
            acc.x += cx * v.x; acc.y += cx * v.y;
            acc.z += cx * v.z; acc.w += cx * v.w;
        }

        // ---- GATv2: unnormalized exp (logits bounded), 4 edges in flight --
        int q  = rows_gat[node];
        int q1 = rows_gat[node + 1];
        int has = (q1 > q);
        float den = 0.f;
        float4 ag = make_float4(0.f, 0.f, 0.f, 0.f);
        for (; q + 4 <= q1; q += 4) {
            int2  pk[4];
            float4 h[4];
            float pp[4];
#pragma unroll
            for (int j = 0; j < 4; ++j) pk[j] = pk_gat[q + j];
#pragma unroll
            for (int j = 0; j < 4; ++j) h[j] = ldb4(&hl[(size_t)pk[j].x * D + lane * 4]);
#pragma unroll
            for (int j = 0; j < 4; ++j)
                pp[j] = wave_sum(gat_partial(h[j], hrv, __int_as_float(pk[j].y), We4, att4));
            float x[4];
#pragma unroll
            for (int j = 0; j < 4; ++j) x[j] = __expf(pp[j]);
            den += (x[0] + x[1]) + (x[2] + x[3]);
#pragma unroll
            for (int j = 0; j < 4; ++j) {
                ag.x += x[j] * h[j].x; ag.y += x[j] * h[j].y;
                ag.z += x[j] * h[j].z; ag.w += x[j] * h[j].w;
            }
        }
        for (; q < q1; ++q) {
            int2 pk = pk_gat[q];
            float4 h = ldb4(&hl[(size_t)pk.x * D + lane * 4]);
            float pp = wave_sum(gat_partial(h, hrv, __int_as_float(pk.y), We4, att4));
            float x = __expf(pp);
            den += x;
            ag.x += x * h.x; ag.y += x * h.y;
            ag.z += x * h.z; ag.w += x * h.w;
        }
        if (has) {
            float inv = 1.0f / den;
            acc.x += ag.x * inv; acc.y += ag.y * inv;
            acc.z += ag.z * inv; acc.w += ag.w * inv;
        }

        // ---- LayerNorm + ReLU ----
        float s_ = acc.x + acc.y + acc.z + acc.w;
        float sq = acc.x * acc.x + acc.y * acc.y + acc.z * acc.z + acc.w * acc.w;
#pragma unroll
        for (int off = 32; off > 0; off >>= 1) {
            s_ += __shfl_xor(s_, off, 64);
            sq += __shfl_xor(sq, off, 64);
        }
        float mu  = s_ * (1.0f / 256.0f);
        float var = sq * (1.0f / 256.0f) - mu * mu;
        float rs  = rsqrtf(var + 1e-5f);
        float4 g = ld4(&gamma[lane * 4]);
        float4 b = ld4(&beta[lane * 4]);
        float4 o;
        o.x = fmaxf(0.f, (acc.x - mu) * rs * g.x + b.x);
        o.y = fmaxf(0.f, (acc.y - mu) * rs * g.y + b.y);
        o.z = fmaxf(0.f, (acc.z - mu) * rs * g.z + b.z);
        o.w = fmaxf(0.f, (acc.w - mu) * rs * g.w + b.w);
        st4(&glom_out[(size_t)node * D + lane * 4], o);
    } else if (gw < 2 * N) {
        // ------------------------------ gin path --------------------------
        int node = gw - N;
        float c = 1.0f + eps[0];
        float4 acc = ldb4(&xb_imm[(size_t)node * D + lane * 4]);
        acc.x *= c; acc.y *= c; acc.z *= c; acc.w *= c;
        int p  = rows_gin[node];
        int p1 = rows_gin[node + 1];
        for (; p + 4 <= p1; p += 4) {
            int s[4];
            float4 v[4];
#pragma unroll
            for (int j = 0; j < 4; ++j) s[j] = src_gin[p + j];
#pragma unroll
            for (int j = 0; j < 4; ++j) v[j] = ldb4(&xb_glom[(size_t)s[j] * D + lane * 4]);
            acc.x += (v[0].x + v[1].x) + (v[2].x + v[3].x);
            acc.y += (v[0].y + v[1].y) + (v[2].y + v[3].y);
            acc.z += (v[0].z + v[1].z) + (v[2].z + v[3].z);
            acc.w += (v[0].w + v[1].w) + (v[2].w + v[3].w);
        }
        for (; p < p1; ++p) {
            int sx = src_gin[p];
            float4 v = ldb4(&xb_glom[(size_t)sx * D + lane * 4]);
            acc.x += v.x; acc.y += v.y; acc.z += v.z; acc.w += v.w;
        }
        ushort4 o;
        o.x = f2bf(acc.x); o.y = f2bf(acc.y); o.z = f2bf(acc.z); o.w = f2bf(acc.w);
        *reinterpret_cast<ushort4*>(agg + (size_t)node * D + lane * 4) = o;
    }
}

// ------------------------------------------------------------------ launch
extern "C" void kernel_launch(void* const* d_in, const int* in_sizes, int n_in,
                              void* d_out, int out_size, void* d_ws, size_t ws_size,
                              hipStream_t stream)
{
    const float* x_glom = (const float*)d_in[0];
    const float* x_imm  = (const float*)d_in[1];
    const float* ew_gg  = (const float*)d_in[2];
    const float* ea_ig  = (const float*)d_in[3];
    const float* W_gcn  = (const float*)d_in[4];
    const float* b_gcn  = (const float*)d_in[5];
    const float* Wl     = (const float*)d_in[6];
    const float* bl     = (const float*)d_in[7];
    const float* Wr     = (const float*)d_in[8];
    const float* br     = (const float*)d_in[9];
    const float* att    = (const float*)d_in[10];
    const float* We     = (const float*)d_in[11];
    const float* b_gat  = (const float*)d_in[12];
    const float* eps    = (const float*)d_in[13];
    const float* W_gin  = (const float*)d_in[14];
    const float* b_gin  = (const float*)d_in[15];
    const float* gamma  = (const float*)d_in[16];
    const float* beta   = (const float*)d_in[17];
    const int*   ei_gg  = (const int*)d_in[18];
    const int*   ei_ig  = (const int*)d_in[19];
    const int*   ei_gi  = (const int*)d_in[20];

    const int N = in_sizes[0] / D;     // 20000
    const int E = in_sizes[2];         // 320000
    const size_t ND = (size_t)N * D;
    const int TPT = (N + 255) / 256;
    const int nbH = (E + EPB - 1) / EPB;       // hist blocks per type (40)

    // ---- workspace layout ----
    char* base = (char*)d_ws;
    size_t off = 0;
    auto alloc = [&](size_t bytes) {
        void* p = base + off;
        off = (off + bytes + 255) & ~(size_t)255;
        return p;
    };
    unsigned short* xb_glom = (unsigned short*)alloc(ND * 2);
    unsigned short* xb_imm  = (unsigned short*)alloc(ND * 2);
    unsigned short* xw_b    = (unsigned short*)alloc(ND * 2);
    unsigned short* hl_b    = (unsigned short*)alloc(ND * 2);
    unsigned short* hr_b    = (unsigned short*)alloc(ND * 2);
    unsigned short* agg_b   = (unsigned short*)alloc(ND * 2);   // aliases blockhist
    unsigned*       blockhist = (unsigned*)agg_b;               // dead before gather
    unsigned short* Wt      = (unsigned short*)alloc(4 * D * D * 2);
    float* dinv    = (float*)alloc((size_t)N * 4);
    int*   rows    = (int*)alloc(3 * (size_t)(N + 1) * 4);
    int*   parts   = (int*)alloc(3 * (size_t)TPT * 4);
    int*   rel32   = (int*)alloc(3 * (size_t)nbH * N * 4);
    unsigned short* rank16 = (unsigned short*)alloc(3 * (size_t)E * 2);
    int2*  pk_gcn  = (int2*)alloc((size_t)E * 8);
    int2*  pk_gat  = (int2*)alloc((size_t)E * 8);
    int*   src_gin = (int*)alloc((size_t)E * 4);

    float* glom_out = (float*)d_out;
    float* imm_out  = (float*)d_out + ND;

    const int n4      = (int)(ND / 4);
    const int nbCast  = (n4 + 255) / 256;          // 5000
    const int nbE     = (E + 255) / 256;           // 1250 scatter blocks/type
    const int nb_3n   = (3 * N + 255) / 256;
    const int nb_2nw  = (2 * N + 3) / 4;
    const int nbProj  = ((N + 255) / 256) * 12;    // 948

    // 1. front: LDS hist (no global atomics) || casts || W transposes
    k_front<<<3 * nbH + 2 * nbCast + 1024, 256, 0, stream>>>(
        x_glom, x_imm, xb_glom, xb_imm,
        W_gcn, Wr, Wl, W_gin, Wt,
        ei_gg, ei_ig, ei_gi,
        blockhist, rank16, n4, nbCast, nbH, E, N);
    // 2-3. scans (scan_part folded into scan_final)
    k_scan_tile<<<dim3(TPT, 3), 256, 0, stream>>>(blockhist, rows, parts, N, TPT, nbH);
    k_scan_final<<<nb_3n, 256, 0, stream>>>(rows, parts, blockhist, rel32,
                                            N, TPT, nbH, E);
    // 4. mid: proj GEMM || scatter (1 random read/edge, L2-resident rel32)
    k_mid<<<nbProj + 3 * nbE, 256, 0, stream>>>(
        xb_glom, xb_imm, Wt, br, bl, xw_b, hr_b, hl_b,
        ei_gg, ei_ig, ei_gi, ew_gg, ea_ig,
        rel32, rank16, pk_gcn, pk_gat, src_gin,
        nbProj, nbE, nbH, E, N, N);
    // 5. dinv from CSR values
    k_deg<<<(N + 255) / 256, 256, 0, stream>>>(rows, pk_gcn, dinv, N);
    // 6. fused gathers (full-wave)
    k_gather_fused<<<nb_2nw, 256, 0, stream>>>(
        xw_b, hl_b, hr_b, dinv,
        rows, pk_gcn,
        rows + (N + 1), pk_gat,
        We, att, b_gcn, b_gat, gamma, beta, glom_out,
        xb_glom, xb_imm, eps,
        rows + 2 * (N + 1), src_gin, agg_b, N);
    // 7. GIN GEMM + fused LN + ReLU
    k_gin_gemm_ln<<<(N + 63) / 64, 256, 0, stream>>>(
        agg_b, Wt + 3 * D * D, b_gin, gamma, beta, imm_out, N);
}

// Round 19
// 206.132 us; speedup vs baseline: 1.1640x; 1.0251x over previous
//
#include <hip/hip_runtime.h>

// HeteroMessagePassingLayer Round 19:
//  - R18 structure, EPB 8192 -> 16384: rel32 9.5->4.8MB (L2-resident),
//    scan inner loops 40->20, blockhist traffic halved
//  - everything else identical to R18 (211.3us)

constexpr int D = 256;
constexpr int EPB_LOG = 14;                 // 16384 edges per hist block
constexpr int EPB = 1 << EPB_LOG;
constexpr int MAXW = 10240;                 // LDS hist words (N<=20480)

typedef __attribute__((ext_vector_type(4))) float f32x4v;
typedef __attribute__((ext_vector_type(8))) short short8;

// ---------------------------------------------------------------- utilities
__device__ __forceinline__ float4 ld4(const float* p) {
    return *reinterpret_cast<const float4*>(p);
}
__device__ __forceinline__ void st4(float* p, float4 v) {
    *reinterpret_cast<float4*>(p) = v;
}
__device__ __forceinline__ unsigned short f2bf(float f) {
    unsigned u = __float_as_uint(f);
    u = u + 0x7FFFu + ((u >> 16) & 1u);
    return (unsigned short)(u >> 16);
}
__device__ __forceinline__ float bf2f(unsigned short u) {
    return __uint_as_float(((unsigned)u) << 16);
}
__device__ __forceinline__ float4 ldb4(const unsigned short* p) {
    ushort4 u = *reinterpret_cast<const ushort4*>(p);
    return make_float4(bf2f(u.x), bf2f(u.y), bf2f(u.z), bf2f(u.w));
}
__device__ __forceinline__ float wave_sum(float p) {
#pragma unroll
    for (int off = 32; off > 0; off >>= 1) p += __shfl_xor(p, off, 64);
    return p;
}
__device__ __forceinline__ float gat_partial(float4 h, float4 hrv, float ea,
                                             float4 We4, float4 att4) {
    float z, pp = 0.f;
    z = h.x + hrv.x + ea * We4.x; z *= (z > 0.f) ? 1.0f : 0.2f; pp += z * att4.x;
    z = h.y + hrv.y + ea * We4.y; z *= (z > 0.f) ? 1.0f : 0.2f; pp += z * att4.y;
    z = h.z + hrv.z + ea * We4.z; z *= (z > 0.f) ? 1.0f : 0.2f; pp += z * att4.z;
    z = h.w + hrv.w + ea * We4.w; z *= (z > 0.f) ? 1.0f : 0.2f; pp += z * att4.w;
    return pp;
}

// ============ k_front: LDS hist blocks FIRST, then casts, then W transposes
__global__ __launch_bounds__(256)
void k_front(const float* __restrict__ x_glom, const float* __restrict__ x_imm,
             unsigned short* __restrict__ xb_glom, unsigned short* __restrict__ xb_imm,
             const float* __restrict__ W0, const float* __restrict__ W1,
             const float* __restrict__ W2, const float* __restrict__ W3,
             unsigned short* __restrict__ Wt,
             const int* __restrict__ ei_gg, const int* __restrict__ ei_ig,
             const int* __restrict__ ei_gi,
             unsigned* __restrict__ blockhist, unsigned short* __restrict__ rank16,
             int n4, int nbCast, int nbH, int E, int N)
{
    __shared__ unsigned ldsh[MAXW];
    int bx = blockIdx.x;
    if (bx < 3 * nbH) {
        // ---- LDS histogram: counts + local rank ----
        int t = bx / nbH;
        int b = bx - t * nbH;
        const int* ei = (t == 0) ? ei_gg : (t == 1) ? ei_ig : ei_gi;
        const int Nw = (N + 1) >> 1;
        for (int w = threadIdx.x; w < Nw; w += 256) ldsh[w] = 0u;
        __syncthreads();
        int e0 = b << EPB_LOG;
#pragma unroll
        for (int it = 0; it < EPB / 256; ++it) {
            int e = e0 + it * 256 + threadIdx.x;
            if (e < E) {
                int d = ei[E + e];
                unsigned sh = (d & 1) * 16;
                unsigned old = atomicAdd(&ldsh[d >> 1], 1u << sh);
                rank16[(size_t)t * E + e] = (unsigned short)((old >> sh) & 0xFFFFu);
            }
        }
        __syncthreads();
        unsigned* dst = blockhist + (size_t)(t * nbH + b) * Nw;
        for (int w = threadIdx.x; w < Nw; w += 256) dst[w] = ldsh[w];
        return;
    }
    bx -= 3 * nbH;
    if (bx < 2 * nbCast) {
        // ---- casts ----
        bool second = (bx >= nbCast);
        int i = (second ? bx - nbCast : bx) * 256 + threadIdx.x;
        if (i < n4) {
            const float* x = second ? x_imm : x_glom;
            unsigned short* y = second ? xb_imm : xb_glom;
            float4 v = ld4(x + (size_t)i * 4);
            ushort4 o;
            o.x = f2bf(v.x); o.y = f2bf(v.y); o.z = f2bf(v.z); o.w = f2bf(v.w);
            *reinterpret_cast<ushort4*>(y + (size_t)i * 4) = o;
        }
        return;
    }
    bx -= 2 * nbCast;
    {
        // ---- W transposes (bf16, order Wgcn, Wr, Wl, Wgin) ----
        int w = bx >> 8;
        int i = ((bx & 255) << 8) + threadIdx.x;
        const float* W = (w == 0) ? W0 : (w == 1) ? W1 : (w == 2) ? W2 : W3;
        int c = i >> 8, k = i & 255;
        Wt[(size_t)w * D * D + i] = f2bf(W[k * D + c]);
    }
}

// --------------------------------------------------------------- scans
__device__ __forceinline__ unsigned hist_get(const unsigned* __restrict__ bh,
                                             int Nw, int nbH, int t, int b, int d)
{
    unsigned w = bh[(size_t)(t * nbH + b) * Nw + (d >> 1)];
    return (w >> ((d & 1) * 16)) & 0xFFFFu;
}

__global__ __launch_bounds__(256)
void k_scan_tile(const unsigned* __restrict__ blockhist, int* __restrict__ rows,
                 int* __restrict__ partials, int N, int TPT, int nbH)
{
    int t = blockIdx.y, tile = blockIdx.x;
    int i = tile * 256 + threadIdx.x;
    const int Nw = (N + 1) >> 1;
    __shared__ int sh[256];
    int v = 0;
    if (i < N)
        for (int b = 0; b < nbH; ++b) v += (int)hist_get(blockhist, Nw, nbH, t, b, i);
    sh[threadIdx.x] = v;
    __syncthreads();
#pragma unroll
    for (int off = 1; off < 256; off <<= 1) {
        int add = (threadIdx.x >= off) ? sh[threadIdx.x - off] : 0;
        __syncthreads();
        sh[threadIdx.x] += add;
        __syncthreads();
    }
    if (i < N) rows[(size_t)t * (N + 1) + i] = sh[threadIdx.x] - v;
    if (threadIdx.x == 255) partials[t * TPT + tile] = sh[255];
}

// finalize rows (per-thread prefix over tile partials);
// emit per-(block,bin) ABSOLUTE i32 bases rel32 = rows+prefix
__global__ void k_scan_final(int* __restrict__ rows, const int* __restrict__ partials,
                             const unsigned* __restrict__ blockhist,
                             int* __restrict__ rel32,
                             int N, int TPT, int nbH, int E)
{
    int i = blockIdx.x * 256 + threadIdx.x;
    if (i >= 3 * N) return;
    int t = i / N, j = i - t * N;
    const int Nw = (N + 1) >> 1;
    int tile = j >> 8;
    int toff = 0;
    for (int tt = 0; tt < tile; ++tt) toff += partials[t * TPT + tt];
    int run = rows[(size_t)t * (N + 1) + j] + toff;
    rows[(size_t)t * (N + 1) + j] = run;
    if (j == 0) rows[(size_t)t * (N + 1) + N] = E;
    int acc = run;
    for (int b = 0; b < nbH; ++b) {
        rel32[(size_t)(t * nbH + b) * N + j] = acc;
        acc += (int)hist_get(blockhist, Nw, nbH, t, b, j);
    }
}

// ============ k_mid: proj GEMM blocks then scatter blocks (one launch)
__global__ __launch_bounds__(256)
void k_mid(const unsigned short* __restrict__ xbg,
           const unsigned short* __restrict__ xbi,
           const unsigned short* __restrict__ Wt,
           const float* __restrict__ br, const float* __restrict__ bl,
           unsigned short* __restrict__ xw, unsigned short* __restrict__ hr,
           unsigned short* __restrict__ hl,
           const int* __restrict__ ei_gg, const int* __restrict__ ei_ig,
           const int* __restrict__ ei_gi, const float* __restrict__ ew_gg,
           const float* __restrict__ ea_ig,
           const int* __restrict__ rel32, const unsigned short* __restrict__ rank16,
           int2* __restrict__ pk_gcn, int2* __restrict__ pk_gat,
           int* __restrict__ src_gin,
           int nbProj, int nbE, int nbH, int E, int N, int M)
{
    int bx = blockIdx.x;
    if (bx < nbProj) {
        // ----------------------------- proj GEMM --------------------------
        int brow = bx / 12;
        int yy   = bx - brow * 12;
        const int lane = threadIdx.x & 63;
        const int wave = threadIdx.x >> 6;
        const int lr = lane & 15;
        const int lk = lane >> 4;
        const int row0 = brow * 256 + wave * 64;

        const unsigned short* A;
        const unsigned short* Bt0;
        int col0;
        if (yy < 8) { A = xbg; Bt0 = Wt;             col0 = yy * 64; }
        else        { A = xbi; Bt0 = Wt + 2 * D * D; col0 = (yy - 8) * 64; }

        const unsigned short* ap[4];
#pragma unroll
        for (int rf = 0; rf < 4; ++rf) {
            int arow = row0 + rf * 16 + lr;
            int arow_c = (arow < M) ? arow : (M - 1);
            ap[rf] = A + (size_t)arow_c * D + lk * 8;
        }
        const unsigned short* bp = Bt0 + (size_t)(col0 + lr) * D + lk * 8;

        f32x4v acc[4][4] = {};
#pragma unroll
        for (int k0 = 0; k0 < 256; k0 += 32) {
            short8 af[4], bf[4];
#pragma unroll
            for (int rf = 0; rf < 4; ++rf)
                af[rf] = *reinterpret_cast<const short8*>(ap[rf] + k0);
#pragma unroll
            for (int nf = 0; nf < 4; ++nf)
                bf[nf] = *reinterpret_cast<const short8*>(bp + (size_t)nf * 16 * D + k0);
#pragma unroll
            for (int rf = 0; rf < 4; ++rf)
#pragma unroll
                for (int nf = 0; nf < 4; ++nf)
                    acc[rf][nf] = __builtin_amdgcn_mfma_f32_16x16x32_bf16(
                        af[rf], bf[nf], acc[rf][nf], 0, 0, 0);
        }

#pragma unroll
        for (int nf = 0; nf < 4; ++nf) {
            int c = col0 + nf * 16 + lr;
            unsigned short* dst;
            int cc;
            float bv;
            if (yy < 8) {
                if (c < 256) { dst = xw; cc = c;       bv = 0.f;    }
                else         { dst = hr; cc = c - 256; bv = br[cc]; }
            } else           { dst = hl; cc = c;       bv = bl[cc]; }
#pragma unroll
            for (int rf = 0; rf < 4; ++rf) {
#pragma unroll
                for (int i = 0; i < 4; ++i) {
                    int r = row0 + rf * 16 + 4 * lk + i;
                    if (r < M)
                        dst[(size_t)r * D + cc] = f2bf(acc[rf][nf][i] + bv);
                }
            }
        }
        return;
    }
    // ------------------- scatter: ONE random 4B read (rel32) per edge ------
    int sx = bx - nbProj;
    int t = sx / nbE;
    int blk = sx - t * nbE;
    int e = blk * 256 + threadIdx.x;
    if (e >= E) return;
    int b = e >> EPB_LOG;
    const int* rel = rel32 + (size_t)(t * nbH + b) * N;
    if (t == 0) {
        int s = ei_gg[e], d = ei_gg[E + e];
        int pos = rel[d] + (int)rank16[e];
        pk_gcn[pos] = make_int2(s, __float_as_int(ew_gg[e]));
    } else if (t == 1) {
        int s = ei_ig[e], d = ei_ig[E + e];
        int pos = rel[d] + (int)rank16[(size_t)E + e];
        pk_gat[pos] = make_int2(s, __float_as_int(ea_ig[e]));
    } else {
        int s = ei_gi[e], d = ei_gi[E + e];
        int pos = rel[d] + (int)rank16[2 * (size_t)E + e];
        src_gin[pos] = s;
    }
}

// ---------- dinv from CSR values: dinv[d] = rsqrt(1 + sum of incoming ew)
__global__ void k_deg(const int* __restrict__ rows, const int2* __restrict__ pk,
                      float* __restrict__ dinv, int N)
{
    int d = blockIdx.x * 256 + threadIdx.x;
    if (d >= N) return;
    float s = 1.0f;
    int p1 = rows[d + 1];
    for (int p = rows[d]; p < p1; ++p) s += __int_as_float(pk[p].y);
    dinv[d] = rsqrtf(s);
}

// ------------------------------------- GIN GEMM + fused LayerNorm + ReLU
__global__ __launch_bounds__(256)
void k_gin_gemm_ln(const unsigned short* __restrict__ A,
                   const unsigned short* __restrict__ Bt,
                   const float* __restrict__ bias,
                   const float* __restrict__ gamma, const float* __restrict__ beta,
                   float* __restrict__ out, int M)
{
    __shared__ float lds_s[4][64];
    __shared__ float lds_q[4][64];
    const int lane = threadIdx.x & 63;
    const int wave = threadIdx.x >> 6;
    const int lr = lane & 15;
    const int lk = lane >> 4;
    const int row0 = blockIdx.x * 64;
    const int col0 = wave * 64;

    const unsigned short* ap[4];
#pragma unroll
    for (int rf = 0; rf < 4; ++rf) {
        int arow = row0 + rf * 16 + lr;
        int arow_c = (arow < M) ? arow : (M - 1);
        ap[rf] = A + (size_t)arow_c * D + lk * 8;
    }
    const unsigned short* bp = Bt + (size_t)(col0 + lr) * D + lk * 8;

    f32x4v acc[4][4] = {};
#pragma unroll
    for (int k0 = 0; k0 < 256; k0 += 32) {
        short8 af[4], bf[4];
#pragma unroll
        for (int rf = 0; rf < 4; ++rf)
            af[rf] = *reinterpret_cast<const short8*>(ap[rf] + k0);
#pragma unroll
        for (int nf = 0; nf < 4; ++nf)
            bf[nf] = *reinterpret_cast<const short8*>(bp + (size_t)nf * 16 * D + k0);
#pragma unroll
        for (int rf = 0; rf < 4; ++rf)
#pragma unroll
            for (int nf = 0; nf < 4; ++nf)
                acc[rf][nf] = __builtin_amdgcn_mfma_f32_16x16x32_bf16(
                    af[rf], bf[nf], acc[rf][nf], 0, 0, 0);
    }

    float bv[4], gv[4], be[4];
#pragma unroll
    for (int nf = 0; nf < 4; ++nf) {
        int c = col0 + nf * 16 + lr;
        bv[nf] = bias[c]; gv[nf] = gamma[c]; be[nf] = beta[c];
    }

#pragma unroll
    for (int rf = 0; rf < 4; ++rf) {
        float ps[4], pq[4];
#pragma unroll
        for (int i = 0; i < 4; ++i) {
            float s = 0.f, q = 0.f;
#pragma unroll
            for (int nf = 0; nf < 4; ++nf) {
                float v = acc[rf][nf][i] + bv[nf];
                acc[rf][nf][i] = v;
                s += v; q += v * v;
            }
            ps[i] = s; pq[i] = q;
        }
#pragma unroll
        for (int off = 1; off < 16; off <<= 1) {
#pragma unroll
            for (int i = 0; i < 4; ++i) {
                ps[i] += __shfl_xor(ps[i], off, 64);
                pq[i] += __shfl_xor(pq[i], off, 64);
            }
        }
        if (lr == 0) {
#pragma unroll
            for (int i = 0; i < 4; ++i) {
                lds_s[wave][rf * 16 + lk * 4 + i] = ps[i];
                lds_q[wave][rf * 16 + lk * 4 + i] = pq[i];
            }
        }
    }
    __syncthreads();

#pragma unroll
    for (int rf = 0; rf < 4; ++rf) {
#pragma unroll
        for (int i = 0; i < 4; ++i) {
            int rl = rf * 16 + 4 * lk + i;
            float s = lds_s[0][rl] + lds_s[1][rl] + lds_s[2][rl] + lds_s[3][rl];
            float q = lds_q[0][rl] + lds_q[1][rl] + lds_q[2][rl] + lds_q[3][rl];
            float mu  = s * (1.0f / 256.0f);
            float var = q * (1.0f / 256.0f) - mu * mu;
            float rs  = rsqrtf(var + 1e-5f);
            int r = row0 + rl;
            if (r < M) {
#pragma unroll
                for (int nf = 0; nf < 4; ++nf) {
                    out[(size_t)r * D + col0 + nf * 16 + lr] =
                        fmaxf(0.f, (acc[rf][nf][i] - mu) * rs * gv[nf] + be[nf]);
                }
            }
        }
    }
}

// ================== fused gather (full-wave): glom GCN+GATv2+LN, GIN agg
__global__ __launch_bounds__(256)
void k_gather_fused(const unsigned short* __restrict__ xw,
                    const unsigned short* __restrict__ hl,
                    const unsigned short* __restrict__ hr,
                    const float* __restrict__ dinv,
                    const int* __restrict__ rows_gcn, const int2* __restrict__ pk_gcn,
                    const int* __restrict__ rows_gat, const int2* __restrict__ pk_gat,
                    const float* __restrict__ We, const float* __restrict__ att,
                    const float* __restrict__ b_gcn, const float* __restrict__ b_gat,
                    const float* __restrict__ gamma, const float* __restrict__ beta,
                    float* __restrict__ glom_out,
                    const unsigned short* __restrict__ xb_glom,
                    const unsigned short* __restrict__ xb_imm,
                    const float* __restrict__ eps,
                    const int* __restrict__ rows_gin, const int* __restrict__ src_gin,
                    unsigned short* __restrict__ agg,
                    int N)
{
    int gw   = __builtin_amdgcn_readfirstlane((blockIdx.x * 256 + threadIdx.x) >> 6);
    int lane = threadIdx.x & 63;

    if (gw < N) {
        // ------------------------------ glom path -------------------------
        int node = gw;
        float4 We4  = ld4(&We[lane * 4]);
        float4 att4 = ld4(&att[lane * 4]);
        float4 hrv  = ldb4(&hr[(size_t)node * D + lane * 4]);

        float di = dinv[node];
        float4 acc = ldb4(&xw[(size_t)node * D + lane * 4]);
        float4 g0  = ld4(&b_gcn[lane * 4]);
        float4 a0  = ld4(&b_gat[lane * 4]);
        float sc0 = di * di;
        acc.x = sc0 * acc.x + g0.x + a0.x;
        acc.y = sc0 * acc.y + g0.y + a0.y;
        acc.z = sc0 * acc.z + g0.z + a0.z;
        acc.w = sc0 * acc.w + g0.w + a0.w;

        // ---- GCN neighbor sum, 4 edges in flight; coef = w*dinv[s]*di ----
        int p  = rows_gcn[node];
        int p1 = rows_gcn[node + 1];
        for (; p + 4 <= p1; p += 4) {
            int2  pk[4];
            float cf[4];
            float4 v[4];
#pragma unroll
            for (int j = 0; j < 4; ++j) pk[j] = pk_gcn[p + j];
#pragma unroll
            for (int j = 0; j < 4; ++j)
                cf[j] = __int_as_float(pk[j].y) * dinv[pk[j].x] * di;
#pragma unroll
            for (int j = 0; j < 4; ++j) v[j] = ldb4(&xw[(size_t)pk[j].x * D + lane * 4]);
#pragma unroll
            for (int j = 0; j < 4; ++j) {
                acc.x += cf[j] * v[j].x; acc.y += cf[j] * v[j].y;
                acc.z += cf[j] * v[j].z; acc.w += cf[j] * v[j].w;
            }
        }
        for (; p < p1; ++p) {
            int2 pk = pk_gcn[p];
            float cx = __int_as_float(pk.y) * dinv[pk.x] * di;
            float4 v = ldb4(&xw[(size_t)pk.x * D + lane * 4]);
            acc.x += cx * v.x; acc.y += cx * v.y;
            acc.z += cx * v.z; acc.w += cx * v.w;
        }

        // ---- GATv2: unnormalized exp (logits bounded), 4 edges in flight --
        int q  = rows_gat[node];
        int q1 = rows_gat[node + 1];
        int has = (q1 > q);
        float den = 0.f;
        float4 ag = make_float4(0.f, 0.f, 0.f, 0.f);
        for (; q + 4 <= q1; q += 4) {
            int2  pk[4];
            float4 h[4];
            float pp[4];
#pragma unroll
            for (int j = 0; j < 4; ++j) pk[j] = pk_gat[q + j];
#pragma unroll
            for (int j = 0; j < 4; ++j) h[j] = ldb4(&hl[(size_t)pk[j].x * D + lane * 4]);
#pragma unroll
            for (int j = 0; j < 4; ++j)
                pp[j] = wave_sum(gat_partial(h[j], hrv, __int_as_float(pk[j].y), We4, att4));
            float x[4];
#pragma unroll
            for (int j = 0; j < 4; ++j) x[j] = __expf(pp[j]);
            den += (x[0] + x[1]) + (x[2] + x[3]);
#pragma unroll
            for (int j = 0; j < 4; ++j) {
                ag.x += x[j] * h[j].x; ag.y += x[j] * h[j].y;
                ag.z += x[j] * h[j].z; ag.w += x[j] * h[j].w;
            }
        }
        for (; q < q1; ++q) {
            int2 pk = pk_gat[q];
            float4 h = ldb4(&hl[(size_t)pk.x * D + lane * 4]);
            float pp = wave_sum(gat_partial(h, hrv, __int_as_float(pk.y), We4, att4));
            float x = __expf(pp);
            den += x;
            ag.x += x * h.x; ag.y += x * h.y;
            ag.z += x * h.z; ag.w += x * h.w;
        }
        if (has) {
            float inv = 1.0f / den;
            acc.x += ag.x * inv; acc.y += ag.y * inv;
            acc.z += ag.z * inv; acc.w += ag.w * inv;
        }

        // ---- LayerNorm + ReLU ----
        float s_ = acc.x + acc.y + acc.z + acc.w;
        float sq = acc.x * acc.x + acc.y * acc.y + acc.z * acc.z + acc.w * acc.w;
#pragma unroll
        for (int off = 32; off > 0; off >>= 1) {
            s_ += __shfl_xor(s_, off, 64);
            sq += __shfl_xor(sq, off, 64);
        }
        float mu  = s_ * (1.0f / 256.0f);
        float var = sq * (1.0f / 256.0f) - mu * mu;
        float rs  = rsqrtf(var + 1e-5f);
        float4 g = ld4(&gamma[lane * 4]);
        float4 b = ld4(&beta[lane * 4]);
        float4 o;
        o.x = fmaxf(0.f, (acc.x - mu) * rs * g.x + b.x);
        o.y = fmaxf(0.f, (acc.y - mu) * rs * g.y + b.y);
        o.z = fmaxf(0.f, (acc.z - mu) * rs * g.z + b.z);
        o.w = fmaxf(0.f, (acc.w - mu) * rs * g.w + b.w);
        st4(&glom_out[(size_t)node * D + lane * 4], o);
    } else if (gw < 2 * N) {
        // ------------------------------ gin path --------------------------
        int node = gw - N;
        float c = 1.0f + eps[0];
        float4 acc = ldb4(&xb_imm[(size_t)node * D + lane * 4]);
        acc.x *= c; acc.y *= c; acc.z *= c; acc.w *= c;
        int p  = rows_gin[node];
        int p1 = rows_gin[node + 1];
        for (; p + 4 <= p1; p += 4) {
            int s[4];
            float4 v[4];
#pragma unroll
            for (int j = 0; j < 4; ++j) s[j] = src_gin[p + j];
#pragma unroll
            for (int j = 0; j < 4; ++j) v[j] = ldb4(&xb_glom[(size_t)s[j] * D + lane * 4]);
            acc.x += (v[0].x + v[1].x) + (v[2].x + v[3].x);
            acc.y += (v[0].y + v[1].y) + (v[2].y + v[3].y);
            acc.z += (v[0].z + v[1].z) + (v[2].z + v[3].z);
            acc.w += (v[0].w + v[1].w) + (v[2].w + v[3].w);
        }
        for (; p < p1; ++p) {
            int sx = src_gin[p];
            float4 v = ldb4(&xb_glom[(size_t)sx * D + lane * 4]);
            acc.x += v.x; acc.y += v.y; acc.z += v.z; acc.w += v.w;
        }
        ushort4 o;
        o.x = f2bf(acc.x); o.y = f2bf(acc.y); o.z = f2bf(acc.z); o.w = f2bf(acc.w);
        *reinterpret_cast<ushort4*>(agg + (size_t)node * D + lane * 4) = o;
    }
}

// ------------------------------------------------------------------ launch
extern "C" void kernel_launch(void* const* d_in, const int* in_sizes, int n_in,
                              void* d_out, int out_size, void* d_ws, size_t ws_size,
                              hipStream_t stream)
{
    const float* x_glom = (const float*)d_in[0];
    const float* x_imm  = (const float*)d_in[1];
    const float* ew_gg  = (const float*)d_in[2];
    const float* ea_ig  = (const float*)d_in[3];
    const float* W_gcn  = (const float*)d_in[4];
    const float* b_gcn  = (const float*)d_in[5];
    const float* Wl     = (const float*)d_in[6];
    const float* bl     = (const float*)d_in[7];
    const float* Wr     = (const float*)d_in[8];
    const float* br     = (const float*)d_in[9];
    const float* att    = (const float*)d_in[10];
    const float* We     = (const float*)d_in[11];
    const float* b_gat  = (const float*)d_in[12];
    const float* eps    = (const float*)d_in[13];
    const float* W_gin  = (const float*)d_in[14];
    const float* b_gin  = (const float*)d_in[15];
    const float* gamma  = (const float*)d_in[16];
    const float* beta   = (const float*)d_in[17];
    const int*   ei_gg  = (const int*)d_in[18];
    const int*   ei_ig  = (const int*)d_in[19];
    const int*   ei_gi  = (const int*)d_in[20];

    const int N = in_sizes[0] / D;     // 20000
    const int E = in_sizes[2];         // 320000
    const size_t ND = (size_t)N * D;
    const int TPT = (N + 255) / 256;
    const int nbH = (E + EPB - 1) / EPB;       // hist blocks per type (20)

    // ---- workspace layout ----
    char* base = (char*)d_ws;
    size_t off = 0;
    auto alloc = [&](size_t bytes) {
        void* p = base + off;
        off = (off + bytes + 255) & ~(size_t)255;
        return p;
    };
    unsigned short* xb_glom = (unsigned short*)alloc(ND * 2);
    unsigned short* xb_imm  = (unsigned short*)alloc(ND * 2);
    unsigned short* xw_b    = (unsigned short*)alloc(ND * 2);
    unsigned short* hl_b    = (unsigned short*)alloc(ND * 2);
    unsigned short* hr_b    = (unsigned short*)alloc(ND * 2);
    unsigned short* agg_b   = (unsigned short*)alloc(ND * 2);   // aliases blockhist
    unsigned*       blockhist = (unsigned*)agg_b;               // dead before gather
    unsigned short* Wt      = (unsigned short*)alloc(4 * D * D * 2);
    float* dinv    = (float*)alloc((size_t)N * 4);
    int*   rows    = (int*)alloc(3 * (size_t)(N + 1) * 4);
    int*   parts   = (int*)alloc(3 * (size_t)TPT * 4);
    int*   rel32   = (int*)alloc(3 * (size_t)nbH * N * 4);
    unsigned short* rank16 = (unsigned short*)alloc(3 * (size_t)E * 2);
    int2*  pk_gcn  = (int2*)alloc((size_t)E * 8);
    int2*  pk_gat  = (int2*)alloc((size_t)E * 8);
    int*   src_gin = (int*)alloc((size_t)E * 4);

    float* glom_out = (float*)d_out;
    float* imm_out  = (float*)d_out + ND;

    const int n4      = (int)(ND / 4);
    const int nbCast  = (n4 + 255) / 256;          // 5000
    const int nbE     = (E + 255) / 256;           // 1250 scatter blocks/type
    const int nb_3n   = (3 * N + 255) / 256;
    const int nb_2nw  = (2 * N + 3) / 4;
    const int nbProj  = ((N + 255) / 256) * 12;    // 948

    // 1. front: LDS hist (no global atomics) || casts || W transposes
    k_front<<<3 * nbH + 2 * nbCast + 1024, 256, 0, stream>>>(
        x_glom, x_imm, xb_glom, xb_imm,
        W_gcn, Wr, Wl, W_gin, Wt,
        ei_gg, ei_ig, ei_gi,
        blockhist, rank16, n4, nbCast, nbH, E, N);
    // 2-3. scans (scan_part folded into scan_final)
    k_scan_tile<<<dim3(TPT, 3), 256, 0, stream>>>(blockhist, rows, parts, N, TPT, nbH);
    k_scan_final<<<nb_3n, 256, 0, stream>>>(rows, parts, blockhist, rel32,
                                            N, TPT, nbH, E);
    // 4. mid: proj GEMM || scatter (1 random read/edge, L2-resident rel32)
    k_mid<<<nbProj + 3 * nbE, 256, 0, stream>>>(
        xb_glom, xb_imm, Wt, br, bl, xw_b, hr_b, hl_b,
        ei_gg, ei_ig, ei_gi, ew_gg, ea_ig,
        rel32, rank16, pk_gcn, pk_gat, src_gin,
        nbProj, nbE, nbH, E, N, N);
    // 5. dinv from CSR values
    k_deg<<<(N + 255) / 256, 256, 0, stream>>>(rows, pk_gcn, dinv, N);
    // 6. fused gathers (full-wave)
    k_gather_fused<<<nb_2nw, 256, 0, stream>>>(
        xw_b, hl_b, hr_b, dinv,
        rows, pk_gcn,
        rows + (N + 1), pk_gat,
        We, att, b_gcn, b_gat, gamma, beta, glom_out,
        xb_glom, xb_imm, eps,
        rows + 2 * (N + 1), src_gin, agg_b, N);
    // 7. GIN GEMM + fused LN + ReLU
    k_gin_gemm_ln<<<(N + 63) / 64, 256, 0, stream>>>(
        agg_b, Wt + 3 * D * D, b_gin, gamma, beta, imm_out, N);
}